// Round 14
// baseline (242.148 us; speedup 1.0000x reference)
//
#include <hip/hip_runtime.h>
#include <math.h>

#define NNODE 2048
#define MCLUS 2048
#define KNBR  32
#define CDIM  256
#define HHEAD 8

typedef __attribute__((ext_vector_type(8))) short bf16x8;
typedef __attribute__((ext_vector_type(4))) float f32x4;

__device__ __forceinline__ float sigf(float x) { return 1.0f / (1.0f + __expf(-x)); }

__device__ __forceinline__ unsigned short f2bf(float f) {
    unsigned x = __float_as_uint(f);
    unsigned r = ((x >> 16) & 1u) + 0x7FFFu;
    return (unsigned short)((x + r) >> 16);
}
__device__ __forceinline__ float bf2f(unsigned short u) {
    return __uint_as_float(((unsigned)u) << 16);
}

__device__ __forceinline__ bool edge_masked(const void* mp, int mode, int e) {
    if (mode & 2) return ((const float*)mp)[e] != 0.0f;
    if (mode & 1) return ((const unsigned char*)mp)[e] != 0;
    return ((const int*)mp)[e] != 0;
}

// ---------------- Kprep: fused k1 (so3 q/key) + kconv + kpre + k0 ----------------
// blocks [0,1152): k1 ; [1152,4160): conv (2048 clus | 192 fcw | 768 wz) ;
// [4160,4448): kpre ; [4448,4512): k0 detect
__global__ __launch_bounds__(256) void kprep(
    const unsigned int* __restrict__ mw, int* __restrict__ flag,
    const float* __restrict__ clus, const float* __restrict__ fcw,
    const float* __restrict__ wz,
    unsigned short* __restrict__ clh, unsigned short* __restrict__ fcwh,
    unsigned short* __restrict__ wzh,
    const float* __restrict__ tgt_emb,
    const float* __restrict__ rm0_w1, const float* __restrict__ rv_w1,
    float* __restrict__ TA, float* __restrict__ CA,
    const float* __restrict__ nodei, const float* __restrict__ W_dot,
    const float* __restrict__ b_dot,
    float* __restrict__ q_ws, unsigned short* __restrict__ keyh)
{
    __shared__ __align__(16) float X[32][256];
    __shared__ int rx[32], rmm[32];
    int b = blockIdx.x, t = threadIdx.x;

    if (b < 1152) {
        // ---- k1: so3_linear for q (nodes) and key (clusters) ----
        int l, vr0, nm, moff;
        if (b < 128)      { l = 0; vr0 = b * 32;         nm = 1; moff = 0; }
        else if (b < 512) { l = 1; vr0 = (b - 128) * 32; nm = 3; moff = 1; }
        else              { l = 2; vr0 = (b - 512) * 32; nm = 5; moff = 4; }
        if (t < 32) {
            int vr = vr0 + t;
            rx[t] = vr / nm;
            rmm[t] = moff + vr % nm;
        }
        __syncthreads();
        for (int e = t; e < 32 * 256; e += 256) {
            int r = e >> 8, c = e & 255;
            int x = rx[r], m = rmm[r];
            const float* src = (x < NNODE) ? (nodei + ((size_t)x * 9 + m) * 256)
                                           : (clus + ((size_t)(x - NNODE) * 9 + m) * 256);
            X[r][c] = src[c];
        }
        __syncthreads();
        int d = t & 31, rg = t >> 5;
        int r0 = rg * 4;
        const float4* wrow = (const float4*)(W_dot + ((size_t)l * 32 + d) * 256);
        float acc[4];
        float bd = (l == 0) ? b_dot[d] : 0.0f;
#pragma unroll
        for (int jj = 0; jj < 4; ++jj) acc[jj] = bd;
        for (int c4 = 0; c4 < 64; ++c4) {
            float4 w = wrow[c4];
#pragma unroll
            for (int jj = 0; jj < 4; ++jj) {
                float4 x4 = *(const float4*)&X[r0 + jj][c4 * 4];
                acc[jj] = fmaf(x4.x, w.x, fmaf(x4.y, w.y, fmaf(x4.z, w.z, fmaf(x4.w, w.w, acc[jj]))));
            }
        }
#pragma unroll
        for (int jj = 0; jj < 4; ++jj) {
            int r = r0 + jj;
            int x = rx[r], m = rmm[r];
            if (x < NNODE) q_ws[((size_t)x * 9 + m) * 32 + d] = acc[jj];
            else           keyh[((size_t)(x - NNODE) * 9 + m) * 32 + d] = f2bf(acc[jj]);
        }
    } else if (b < 4160) {
        int bb = b - 1152;
        if (bb < MCLUS) {
            size_t base = (size_t)bb * 2304;
#pragma unroll
            for (int r = 0; r < 9; ++r) {
                int o = r * 256 + t;
                clh[base + o] = f2bf(clus[base + o]);
            }
        } else if (bb < MCLUS + 192) {
            int off = (bb - MCLUS) * 256 + t;
            fcwh[off] = f2bf(fcw[off]);
        } else {
            int off = (bb - MCLUS - 192) * 256 + t;
            wzh[off] = f2bf(wz[off]);
        }
    } else if (b < 4448) {
        int bb = b - 4160;
        int slot = t & 31, j = slot & 15, mlp = slot >> 4;
        const float* w1 = mlp ? rv_w1 : rm0_w1;
        if (bb < 32) {
            int a = bb * 8 + (t >> 5);
            const float* x = tgt_emb + (size_t)a * 128;
            const float* w = w1 + j * 416 + 32;
            float acc = 0.0f, acc2 = 0.0f;
            for (int i = 0; i < 128; i += 8) {
                acc  = fmaf(x[i], w[i], fmaf(x[i+1], w[i+1], fmaf(x[i+2], w[i+2], fmaf(x[i+3], w[i+3], acc))));
                acc2 = fmaf(x[i+4], w[i+4], fmaf(x[i+5], w[i+5], fmaf(x[i+6], w[i+6], fmaf(x[i+7], w[i+7], acc2))));
            }
            TA[a * 32 + slot] = acc + acc2;
        } else {
            int m = (bb - 32) * 8 + (t >> 5);
            const float* x = clus + (size_t)m * 2304;
            const float* w = w1 + j * 416 + 160;
            float acc = 0.0f, acc2 = 0.0f;
            for (int i = 0; i < 256; i += 8) {
                acc  = fmaf(x[i], w[i], fmaf(x[i+1], w[i+1], fmaf(x[i+2], w[i+2], fmaf(x[i+3], w[i+3], acc))));
                acc2 = fmaf(x[i+4], w[i+4], fmaf(x[i+5], w[i+5], fmaf(x[i+6], w[i+6], fmaf(x[i+7], w[i+7], acc2))));
            }
            CA[m * 32 + slot] = acc + acc2;
        }
    } else {
        int i = (b - 4448) * 256 + t;
        unsigned int w = mw[i];
        int vb = (w != 0u && w != 1u && w != 0x3F800000u) ? 1 : 0;
        int vf = (w == 0x3F800000u) ? 1 : 0;
        unsigned long long bal_b = __ballot(vb);
        unsigned long long bal_f = __ballot(vf);
        if ((t & 63) == 0) {
            if (bal_b) atomicOr(flag, 1);
            if (bal_f) atomicOr(flag, 2);
        }
    }
}

// ---------------- K2ab: fused edge pipeline (MFMA phase B) ----------------
__device__ __forceinline__ float lnsilu16(float x, float g, float b) {
    float s = x;
#pragma unroll
    for (int m = 1; m < 16; m <<= 1) s += __shfl_xor(s, m, 16);
    float mu = s * 0.0625f;
    float d = x - mu;
    float s2 = d * d;
#pragma unroll
    for (int m = 1; m < 16; m <<= 1) s2 += __shfl_xor(s2, m, 16);
    float y = d * rsqrtf(s2 * 0.0625f + 1e-5f) * g + b;
    return y * sigf(y);
}

__global__ __launch_bounds__(256, 2) void k2ab(
    const float* __restrict__ attn_weight, const void* __restrict__ mask,
    const int* __restrict__ mflag,
    const int* __restrict__ f_idx, const float* __restrict__ edge_vec,
    const int* __restrict__ atom_num,
    const float* __restrict__ q_ws, const unsigned short* __restrict__ keyh,
    const float* __restrict__ TA, const float* __restrict__ CA,
    const float* __restrict__ rm0_w1, const float* __restrict__ rm0_b1,
    const float* __restrict__ rm0_g1, const float* __restrict__ rm0_be1,
    const float* __restrict__ rm0_w2, const float* __restrict__ rm0_b2,
    const float* __restrict__ rm0_g2, const float* __restrict__ rm0_be2,
    const float* __restrict__ rm0_w3, const float* __restrict__ rm0_b3,
    const unsigned short* __restrict__ fcwh, const float* __restrict__ fcb,
    const float* __restrict__ an_g, const float* __restrict__ an_b,
    const float* __restrict__ alpha_dot,
    const float* __restrict__ rv_w1, const float* __restrict__ rv_b1,
    const float* __restrict__ rv_g1, const float* __restrict__ rv_be1,
    const float* __restrict__ rv_w2, const float* __restrict__ rv_b2,
    const float* __restrict__ rv_g2, const float* __restrict__ rv_be2,
    float* __restrict__ al_g, float* __restrict__ h2v_g)
{
    __shared__ float qn[288];
    __shared__ float Ts[32];
    __shared__ float shS[32][9];
    __shared__ __align__(16) unsigned char poolS[32 * 200 * 2];
    float (*awS)[32] = (float(*)[32])poolS;
    float (*caS)[32] = (float(*)[32])(poolS + 4096);
    unsigned short (*mwbS)[200] = (unsigned short(*)[200])poolS;
    __shared__ unsigned short KDSh[32][96];   // pre-dotted key (bf16)
    __shared__ float h2mS[32][17];
    __shared__ float lgS[32][8];
    __shared__ float mxS[8], invS[8];
    __shared__ int idxk[32], maskk[32];

    int n = blockIdx.x, t = threadIdx.x;
    int mode = mflag[0];

    for (int i = t; i < 288; i += 256) qn[i] = q_ws[(size_t)n * 288 + i];
    if (t < 32) {
        int an = atom_num[n];
        Ts[t] = TA[an * 32 + t];
        int e = n * KNBR + t;
        idxk[t] = f_idx[e];
        maskk[t] = edge_masked(mask, mode, e) ? 1 : 0;
        float vx = edge_vec[(size_t)e * 3 + 0];
        float vy = edge_vec[(size_t)e * 3 + 1];
        float vz = edge_vec[(size_t)e * 3 + 2];
        float inv = 1.0f / (sqrtf(vx * vx + vy * vy + vz * vz) + 1e-12f);
        float x = vx * inv, y = vy * inv, z = vz * inv;
        shS[t][0] = 0.28209479177387814f;
        shS[t][1] = 0.4886025119029199f * y;
        shS[t][2] = 0.4886025119029199f * z;
        shS[t][3] = 0.4886025119029199f * x;
        shS[t][4] = 1.0925484305920792f * x * y;
        shS[t][5] = 1.0925484305920792f * y * z;
        shS[t][6] = 0.31539156525252005f * (3.0f * z * z - 1.0f);
        shS[t][7] = 1.0925484305920792f * x * z;
        shS[t][8] = 0.5462742152960396f * (x * x - y * y);
    }
    __syncthreads();
    for (int e2 = t; e2 < 1024; e2 += 256) {
        int ek = e2 >> 5, i = e2 & 31;
        awS[ek][i] = maskk[ek] ? 0.0f : attn_weight[((size_t)(n * KNBR + ek)) * 32 + i];
        caS[ek][i] = CA[(size_t)idxk[ek] * 32 + i];
    }
    // stage pre-dotted key rows: KDSh[e][p*32+c] = bf16(<key_l, sh_l>)
    for (int i = t; i < 32 * 96; i += 256) {
        int e = i / 96, j = i - e * 96;
        int p = j >> 5, c = j & 31;
        const unsigned short* kr = keyh + (size_t)idxk[e] * 288;
        float v;
        if (p == 0)      v = bf2f(kr[c]) * shS[e][0];
        else if (p == 1) v = bf2f(kr[32 + c]) * shS[e][1] + bf2f(kr[64 + c]) * shS[e][2]
                           + bf2f(kr[96 + c]) * shS[e][3];
        else             v = bf2f(kr[128 + c]) * shS[e][4] + bf2f(kr[160 + c]) * shS[e][5]
                           + bf2f(kr[192 + c]) * shS[e][6] + bf2f(kr[224 + c]) * shS[e][7]
                           + bf2f(kr[256 + c]) * shS[e][8];
        KDSh[e][j] = f2bf(v);
    }
    __syncthreads();

    // ===== phase A: edge MLPs (wave-parallel, 16-lane groups, 2-way fma trees) ====
    {
        int g = t >> 4, j = t & 15;
        for (int ee = 0; ee < 2; ++ee) {
            int e = g + ee * 16;
            float accm = rm0_b1[j] + Ts[j] + caS[e][j];
            float accv = rv_b1[j] + Ts[16 + j] + caS[e][16 + j];
            float accm2 = 0.0f, accv2 = 0.0f;
            const float* w1m = rm0_w1 + j * 416;
            const float* w1v = rv_w1 + j * 416;
#pragma unroll
            for (int i = 0; i < 32; i += 8) {
                float a0 = awS[e][i], a1 = awS[e][i+1], a2 = awS[e][i+2], a3 = awS[e][i+3];
                float a4 = awS[e][i+4], a5 = awS[e][i+5], a6 = awS[e][i+6], a7 = awS[e][i+7];
                accm  = fmaf(a0, w1m[i], fmaf(a1, w1m[i+1], fmaf(a2, w1m[i+2], fmaf(a3, w1m[i+3], accm))));
                accm2 = fmaf(a4, w1m[i+4], fmaf(a5, w1m[i+5], fmaf(a6, w1m[i+6], fmaf(a7, w1m[i+7], accm2))));
                accv  = fmaf(a0, w1v[i], fmaf(a1, w1v[i+1], fmaf(a2, w1v[i+2], fmaf(a3, w1v[i+3], accv))));
                accv2 = fmaf(a4, w1v[i+4], fmaf(a5, w1v[i+5], fmaf(a6, w1v[i+6], fmaf(a7, w1v[i+7], accv2))));
            }
            accm += accm2; accv += accv2;
            float hm = lnsilu16(accm, rm0_g1[j], rm0_be1[j]);
            float hv = lnsilu16(accv, rv_g1[j], rv_be1[j]);
            float am2 = rm0_b2[j], av2 = rv_b2[j];
            float am2b = 0.0f, av2b = 0.0f;
#pragma unroll
            for (int i = 0; i < 8; ++i) {
                am2  = fmaf(__shfl(hm, i, 16), rm0_w2[j * 16 + i], am2);
                am2b = fmaf(__shfl(hm, 8 + i, 16), rm0_w2[j * 16 + 8 + i], am2b);
                av2  = fmaf(__shfl(hv, i, 16), rv_w2[j * 16 + i], av2);
                av2b = fmaf(__shfl(hv, 8 + i, 16), rv_w2[j * 16 + 8 + i], av2b);
            }
            am2 += am2b; av2 += av2b;
            float h2m = lnsilu16(am2, rm0_g2[j], rm0_be2[j]);
            float h2v = lnsilu16(av2, rv_g2[j], rv_be2[j]);
            h2v_g[(size_t)n * 512 + e * 16 + j] = h2v;
            h2mS[e][j] = h2m;
        }
    }
    __syncthreads();   // awS/caS dead from here; pool becomes mwbS

    // ===== phase M: mwb[e][d] = bf16((rm0 layer3) * m0), uniform bb =====
#pragma unroll
    for (int bb = 0; bb < 6; ++bb) {
#pragma unroll
        for (int r2 = 0; r2 < 4; ++r2) {
            int oi = r2 * 256 + t;          // 0..1023
            int e = oi >> 5, c = oi & 31;
            int d = bb * 32 + c;
            const float4* w3 = (const float4*)(rm0_w3 + d * 16);
            float ew = rm0_b3[d], ew2 = 0.0f;
            {
                float4 w0 = w3[0], w1 = w3[1], w2 = w3[2], w3v = w3[3];
                ew  = fmaf(h2mS[e][0], w0.x, fmaf(h2mS[e][1], w0.y,
                      fmaf(h2mS[e][2], w0.z, fmaf(h2mS[e][3], w0.w, ew))));
                ew2 = fmaf(h2mS[e][4], w1.x, fmaf(h2mS[e][5], w1.y,
                      fmaf(h2mS[e][6], w1.z, fmaf(h2mS[e][7], w1.w, ew2))));
                ew  = fmaf(h2mS[e][8], w2.x, fmaf(h2mS[e][9], w2.y,
                      fmaf(h2mS[e][10], w2.z, fmaf(h2mS[e][11], w2.w, ew))));
                ew2 = fmaf(h2mS[e][12], w3v.x, fmaf(h2mS[e][13], w3v.y,
                      fmaf(h2mS[e][14], w3v.z, fmaf(h2mS[e][15], w3v.w, ew2))));
            }
            ew += ew2;
            float m0v;
            if (bb == 0)      m0v = qn[c] * shS[e][0];
            else if (bb == 1) m0v = qn[32 + c] * shS[e][1] + qn[64 + c] * shS[e][2]
                                  + qn[96 + c] * shS[e][3];
            else if (bb == 2) m0v = qn[128 + c] * shS[e][4] + qn[160 + c] * shS[e][5]
                                  + qn[192 + c] * shS[e][6] + qn[224 + c] * shS[e][7]
                                  + qn[256 + c] * shS[e][8];
            else              m0v = bf2f(KDSh[e][(bb - 3) * 32 + c]);
            mwbS[e][d] = f2bf(ew * m0v);
        }
    }
    __syncthreads();

    // ===== phase B: af = mwa @ fcw^T + fcb via MFMA; LN + smooth_leaky + logits ===
    {
        int wid = t >> 6, lane = t & 63;
        int lrow = lane & 15, kgrp = lane >> 4;
        f32x4 acc[4][2];
#pragma unroll
        for (int i = 0; i < 4; ++i)
#pragma unroll
            for (int m = 0; m < 2; ++m) acc[i][m] = (f32x4){0.f, 0.f, 0.f, 0.f};

#pragma unroll
        for (int ntl = 0; ntl < 4; ++ntl) {
            int col = wid * 64 + ntl * 16 + lrow;
            const bf16x8* brow = (const bf16x8*)(fcwh + (size_t)col * 192);
            bf16x8 bf[6];
#pragma unroll
            for (int kk = 0; kk < 6; ++kk) bf[kk] = brow[kk * 4 + kgrp];
#pragma unroll
            for (int kk = 0; kk < 6; ++kk) {
#pragma unroll
                for (int m = 0; m < 2; ++m) {
                    bf16x8 a8 = *(const bf16x8*)&mwbS[m * 16 + lrow][kk * 32 + kgrp * 8];
                    acc[ntl][m] = __builtin_amdgcn_mfma_f32_16x16x32_bf16(a8, bf[kk], acc[ntl][m], 0, 0, 0);
                }
            }
        }
#pragma unroll
        for (int ntl = 0; ntl < 4; ++ntl) {
            float fb = fcb[wid * 64 + ntl * 16 + lrow];
#pragma unroll
            for (int m = 0; m < 2; ++m)
#pragma unroll
                for (int r = 0; r < 4; ++r) acc[ntl][m][r] += fb;
        }
        float ang0 = an_g[lrow], ang1 = an_g[16 + lrow];
        float anb0 = an_b[lrow], anb1 = an_b[16 + lrow];
#pragma unroll
        for (int hh = 0; hh < 2; ++hh) {
            int h = wid * 2 + hh;
            float ad0 = alpha_dot[h * 32 + lrow], ad1 = alpha_dot[h * 32 + 16 + lrow];
#pragma unroll
            for (int m = 0; m < 2; ++m) {
#pragma unroll
                for (int r = 0; r < 4; ++r) {
                    float a = acc[2 * hh][m][r], b = acc[2 * hh + 1][m][r];
                    float su = a + b;
#pragma unroll
                    for (int mm = 1; mm < 16; mm <<= 1) su += __shfl_xor(su, mm, 16);
                    float mu = su * (1.0f / 32.0f);
                    float da = a - mu, db = b - mu;
                    float v2 = da * da + db * db;
#pragma unroll
                    for (int mm = 1; mm < 16; mm <<= 1) v2 += __shfl_xor(v2, mm, 16);
                    float rs = rsqrtf(v2 * (1.0f / 32.0f) + 1e-5f);
                    float y0 = da * rs * ang0 + anb0;
                    float y1 = db * rs * ang1 + anb1;
                    float sl0 = 0.6f * y0 + 0.4f * y0 * (2.0f * sigf(y0) - 1.0f);
                    float sl1 = 0.6f * y1 + 0.4f * y1 * (2.0f * sigf(y1) - 1.0f);
                    float lg = sl0 * ad0 + sl1 * ad1;
#pragma unroll
                    for (int mm = 1; mm < 16; mm <<= 1) lg += __shfl_xor(lg, mm, 16);
                    if (lrow == 0) {
                        int e = m * 16 + kgrp * 4 + r;
                        lgS[e][h] = maskk[e] ? -1e9f : lg;
                    }
                }
            }
        }
    }
    __syncthreads();

    // ===== softmax over k, write alpha =====
    if (t < 8) {
        float mx = -1e30f;
#pragma unroll
        for (int k = 0; k < 32; ++k) mx = fmaxf(mx, lgS[k][t]);
        float sum = 0.0f;
#pragma unroll
        for (int k = 0; k < 32; ++k) sum += __expf(lgS[k][t] - mx);
        mxS[t] = mx;
        invS[t] = 1.0f / sum;
    }
    __syncthreads();
    {
        int k = t >> 3, h = t & 7;
        al_g[(size_t)n * 256 + t] = __expf(lgS[k][h] - mxS[h]) * invS[h];
    }
}

// ---------------- K2c: gather + aggregate (latency-bound, high-occupancy) --------
__global__ __launch_bounds__(256) void k2c(
    const float* __restrict__ al_g, const float* __restrict__ h2v_g,
    const int* __restrict__ f_idx, const unsigned short* __restrict__ clh,
    const float* __restrict__ rv_w3, const float* __restrict__ rv_b3,
    float* __restrict__ outpre)
{
    __shared__ float alS[256];        // [k][8]
    __shared__ float h2S[32][16];
    __shared__ int idxS[32];
    int n = blockIdx.x, t = threadIdx.x;
    alS[t] = al_g[(size_t)n * 256 + t];
    if (t < 32) idxS[t] = f_idx[n * KNBR + t];
    for (int i = t; i < 512; i += 256) h2S[i >> 4][i & 15] = h2v_g[(size_t)n * 512 + i];
    __syncthreads();

    int c = t, h = c >> 5;
    float avr[32];
    {
        float w3r[16];
        const float4* w3p = (const float4*)(rv_w3 + c * 16);
#pragma unroll
        for (int i4 = 0; i4 < 4; ++i4) {
            float4 w = w3p[i4];
            w3r[i4 * 4 + 0] = w.x; w3r[i4 * 4 + 1] = w.y;
            w3r[i4 * 4 + 2] = w.z; w3r[i4 * 4 + 3] = w.w;
        }
        float b3c = rv_b3[c];
#pragma unroll
        for (int k = 0; k < 32; ++k) {
            float vw = b3c;
#pragma unroll
            for (int i = 0; i < 16; ++i) vw = fmaf(h2S[k][i], w3r[i], vw);
            avr[k] = alS[k * 8 + h] * vw;
        }
    }

    float acc[9];
#pragma unroll
    for (int m = 0; m < 9; ++m) acc[m] = 0.0f;
#pragma unroll 4
    for (int k = 0; k < 32; ++k) {
        const unsigned short* crow = clh + (size_t)idxS[k] * 2304 + c;
        float av = avr[k];
#pragma unroll
        for (int m = 0; m < 9; ++m) acc[m] = fmaf(av, bf2f(crow[m * 256]), acc[m]);
    }
#pragma unroll
    for (int m = 0; m < 9; ++m) outpre[((size_t)n * 9 + m) * 256 + c] = acc[m];
}

// ---------------- K5: final so3_linear via MFMA (wzh bf16), in-place on d_out ----
__global__ __launch_bounds__(256) void k5_final(
    const unsigned short* __restrict__ wzh, const float* __restrict__ bz,
    float* __restrict__ io)
{
    __shared__ __align__(16) unsigned short Xb[32][264];
    __shared__ int rr[32];
    int b = blockIdx.x, t = threadIdx.x;
    int l, vr0, nm, moff;
    if (b < 64)       { l = 0; vr0 = b * 32;         nm = 1; moff = 0; }
    else if (b < 256) { l = 1; vr0 = (b - 64) * 32;  nm = 3; moff = 1; }
    else              { l = 2; vr0 = (b - 256) * 32; nm = 5; moff = 4; }
    if (t < 32) {
        int vr = vr0 + t;
        int n = vr / nm, m = moff + vr % nm;
        rr[t] = n * 9 + m;
    }
    __syncthreads();
    for (int e = t; e < 32 * 256; e += 256) {
        int r = e >> 8, c = e & 255;
        Xb[r][c] = f2bf(io[(size_t)rr[r] * 256 + c]);
    }
    __syncthreads();

    int wid = t >> 6, lane = t & 63;
    int lrow = lane & 15, kgrp = lane >> 4;
    f32x4 acc[2][4];
#pragma unroll
    for (int mt = 0; mt < 2; ++mt)
#pragma unroll
        for (int ntl = 0; ntl < 4; ++ntl) acc[mt][ntl] = (f32x4){0.f, 0.f, 0.f, 0.f};

#pragma unroll
    for (int ntl = 0; ntl < 4; ++ntl) {
        int dcol = wid * 64 + ntl * 16 + lrow;
        const bf16x8* brow = (const bf16x8*)(wzh + ((size_t)l * 256 + dcol) * 256);
#pragma unroll
        for (int kk = 0; kk < 8; ++kk) {
            bf16x8 b8 = brow[kk * 4 + kgrp];
#pragma unroll
            for (int mt = 0; mt < 2; ++mt) {
                bf16x8 a8 = *(const bf16x8*)&Xb[mt * 16 + lrow][kk * 32 + kgrp * 8];
                acc[mt][ntl] = __builtin_amdgcn_mfma_f32_16x16x32_bf16(a8, b8, acc[mt][ntl], 0, 0, 0);
            }
        }
    }
#pragma unroll
    for (int ntl = 0; ntl < 4; ++ntl) {
        int dcol = wid * 64 + ntl * 16 + lrow;
        float bias = (l == 0) ? bz[dcol] : 0.0f;
#pragma unroll
        for (int mt = 0; mt < 2; ++mt) {
#pragma unroll
            for (int r = 0; r < 4; ++r) {
                int row = mt * 16 + kgrp * 4 + r;
                io[(size_t)rr[row] * 256 + dcol] = acc[mt][ntl][r] + bias;
            }
        }
    }
}

// ---------------- launch ----------------
extern "C" void kernel_launch(void* const* d_in, const int* in_sizes, int n_in,
                              void* d_out, int out_size, void* d_ws, size_t ws_size,
                              hipStream_t stream)
{
    (void)in_sizes; (void)n_in; (void)out_size; (void)ws_size;

    const float* node_irreps = (const float*)d_in[1];
    const float* edge_vec    = (const float*)d_in[3];
    const float* attn_weight = (const float*)d_in[4];
    const int*   atom_num    = (const int*)d_in[5];
    const void*  attn_mask   = d_in[6];
    const int*   f_idx       = (const int*)d_in[7];
    const float* clus        = (const float*)d_in[8];
    const float* tgt_emb     = (const float*)d_in[9];
    const float* W_dot       = (const float*)d_in[10];
    const float* b_dot       = (const float*)d_in[11];
    const float* rm0_w1 = (const float*)d_in[12];
    const float* rm0_b1 = (const float*)d_in[13];
    const float* rm0_g1 = (const float*)d_in[14];
    const float* rm0_be1 = (const float*)d_in[15];
    const float* rm0_w2 = (const float*)d_in[16];
    const float* rm0_b2 = (const float*)d_in[17];
    const float* rm0_g2 = (const float*)d_in[18];
    const float* rm0_be2 = (const float*)d_in[19];
    const float* rm0_w3 = (const float*)d_in[20];
    const float* rm0_b3 = (const float*)d_in[21];
    const float* fcw = (const float*)d_in[22];
    const float* fcb = (const float*)d_in[23];
    const float* an_g = (const float*)d_in[24];
    const float* an_b = (const float*)d_in[25];
    const float* alpha_dot = (const float*)d_in[26];
    const float* rv_w1 = (const float*)d_in[27];
    const float* rv_b1 = (const float*)d_in[28];
    const float* rv_g1 = (const float*)d_in[29];
    const float* rv_be1 = (const float*)d_in[30];
    const float* rv_w2 = (const float*)d_in[31];
    const float* rv_b2 = (const float*)d_in[32];
    const float* rv_g2 = (const float*)d_in[33];
    const float* rv_be2 = (const float*)d_in[34];
    const float* rv_w3 = (const float*)d_in[35];
    const float* rv_b3 = (const float*)d_in[36];
    const float* wz = (const float*)d_in[37];
    const float* bz = (const float*)d_in[38];

    float* ws = (float*)d_ws;
    int* flag = (int*)d_ws;
    float* q_ws = ws + 16;                                                   // 2048*288 f32
    unsigned short* keyh = (unsigned short*)(q_ws + (size_t)NNODE * 288);    // 2048*288 bf16
    float* TA_ws = (float*)(keyh + (size_t)MCLUS * 288);                     // 256*32
    float* CA_ws = TA_ws + 256 * 32;                                         // 2048*32
    unsigned short* clh = (unsigned short*)(CA_ws + (size_t)MCLUS * 32);     // 2048*2304 bf16
    float* al_ws = (float*)(clh + (size_t)MCLUS * 2304);                     // 2048*256
    float* h2v_ws = al_ws + (size_t)NNODE * 256;                             // 2048*512
    unsigned short* fcwh = (unsigned short*)(h2v_ws + (size_t)NNODE * 512);  // 256*192 bf16
    unsigned short* wzh = fcwh + 256 * 192;                                  // 3*256*256 bf16
    float* outpre = (float*)d_out;

    hipMemsetAsync(flag, 0, sizeof(int), stream);
    kprep<<<4512, 256, 0, stream>>>(
        (const unsigned int*)attn_mask, flag,
        clus, fcw, wz, clh, fcwh, wzh,
        tgt_emb, rm0_w1, rv_w1, TA_ws, CA_ws,
        node_irreps, W_dot, b_dot, q_ws, keyh);
    k2ab<<<NNODE, 256, 0, stream>>>(
        attn_weight, attn_mask, flag, f_idx, edge_vec, atom_num,
        q_ws, keyh, TA_ws, CA_ws,
        rm0_w1, rm0_b1, rm0_g1, rm0_be1, rm0_w2, rm0_b2, rm0_g2, rm0_be2, rm0_w3, rm0_b3,
        fcwh, fcb, an_g, an_b, alpha_dot,
        rv_w1, rv_b1, rv_g1, rv_be1, rv_w2, rv_b2, rv_g2, rv_be2,
        al_ws, h2v_ws);
    k2c<<<NNODE, 256, 0, stream>>>(al_ws, h2v_ws, f_idx, clh, rv_w3, rv_b3, outpre);
    k5_final<<<576, 256, 0, stream>>>(wzh, bz, outpre);
}

// Round 15
// 227.880 us; speedup vs baseline: 1.0626x; 1.0626x over previous
//
#include <hip/hip_runtime.h>
#include <math.h>

#define NNODE 2048
#define MCLUS 2048
#define KNBR  32
#define CDIM  256
#define HHEAD 8

typedef __attribute__((ext_vector_type(8))) short bf16x8;
typedef __attribute__((ext_vector_type(4))) float f32x4;

__device__ __forceinline__ float sigf(float x) { return 1.0f / (1.0f + __expf(-x)); }

__device__ __forceinline__ unsigned short f2bf(float f) {
    unsigned x = __float_as_uint(f);
    unsigned r = ((x >> 16) & 1u) + 0x7FFFu;
    return (unsigned short)((x + r) >> 16);
}
__device__ __forceinline__ float bf2f(unsigned short u) {
    return __uint_as_float(((unsigned)u) << 16);
}

__device__ __forceinline__ bool edge_masked(const void* mp, int mode, int e) {
    if (mode & 2) return ((const float*)mp)[e] != 0.0f;
    if (mode & 1) return ((const unsigned char*)mp)[e] != 0;
    return ((const int*)mp)[e] != 0;
}

// ---------------- Kprep: fused k1 (so3 q/key) + kconv + kpre + k0 ----------------
// blocks [0,1152): k1 ; [1152,4160): conv (2048 clus | 192 fcw | 768 wz) ;
// [4160,4448): kpre ; [4448,4512): k0 detect
__global__ __launch_bounds__(256) void kprep(
    const unsigned int* __restrict__ mw, int* __restrict__ flag,
    const float* __restrict__ clus, const float* __restrict__ fcw,
    const float* __restrict__ wz,
    unsigned short* __restrict__ clh, unsigned short* __restrict__ fcwh,
    unsigned short* __restrict__ wzh,
    const float* __restrict__ tgt_emb,
    const float* __restrict__ rm0_w1, const float* __restrict__ rv_w1,
    float* __restrict__ TA, float* __restrict__ CA,
    const float* __restrict__ nodei, const float* __restrict__ W_dot,
    const float* __restrict__ b_dot,
    float* __restrict__ q_ws, unsigned short* __restrict__ keyh)
{
    __shared__ __align__(16) float X[32][256];
    __shared__ int rx[32], rmm[32];
    int b = blockIdx.x, t = threadIdx.x;

    if (b < 1152) {
        int l, vr0, nm, moff;
        if (b < 128)      { l = 0; vr0 = b * 32;         nm = 1; moff = 0; }
        else if (b < 512) { l = 1; vr0 = (b - 128) * 32; nm = 3; moff = 1; }
        else              { l = 2; vr0 = (b - 512) * 32; nm = 5; moff = 4; }
        if (t < 32) {
            int vr = vr0 + t;
            rx[t] = vr / nm;
            rmm[t] = moff + vr % nm;
        }
        __syncthreads();
        for (int e = t; e < 32 * 256; e += 256) {
            int r = e >> 8, c = e & 255;
            int x = rx[r], m = rmm[r];
            const float* src = (x < NNODE) ? (nodei + ((size_t)x * 9 + m) * 256)
                                           : (clus + ((size_t)(x - NNODE) * 9 + m) * 256);
            X[r][c] = src[c];
        }
        __syncthreads();
        int d = t & 31, rg = t >> 5;
        int r0 = rg * 4;
        const float4* wrow = (const float4*)(W_dot + ((size_t)l * 32 + d) * 256);
        float acc[4];
        float bd = (l == 0) ? b_dot[d] : 0.0f;
#pragma unroll
        for (int jj = 0; jj < 4; ++jj) acc[jj] = bd;
        for (int c4 = 0; c4 < 64; ++c4) {
            float4 w = wrow[c4];
#pragma unroll
            for (int jj = 0; jj < 4; ++jj) {
                float4 x4 = *(const float4*)&X[r0 + jj][c4 * 4];
                acc[jj] = fmaf(x4.x, w.x, fmaf(x4.y, w.y, fmaf(x4.z, w.z, fmaf(x4.w, w.w, acc[jj]))));
            }
        }
#pragma unroll
        for (int jj = 0; jj < 4; ++jj) {
            int r = r0 + jj;
            int x = rx[r], m = rmm[r];
            if (x < NNODE) q_ws[((size_t)x * 9 + m) * 32 + d] = acc[jj];
            else           keyh[((size_t)(x - NNODE) * 9 + m) * 32 + d] = f2bf(acc[jj]);
        }
    } else if (b < 4160) {
        int bb = b - 1152;
        if (bb < MCLUS) {
            size_t base = (size_t)bb * 2304;
#pragma unroll
            for (int r = 0; r < 9; ++r) {
                int o = r * 256 + t;
                clh[base + o] = f2bf(clus[base + o]);
            }
        } else if (bb < MCLUS + 192) {
            int off = (bb - MCLUS) * 256 + t;
            fcwh[off] = f2bf(fcw[off]);
        } else {
            int off = (bb - MCLUS - 192) * 256 + t;
            wzh[off] = f2bf(wz[off]);
        }
    } else if (b < 4448) {
        int bb = b - 4160;
        int slot = t & 31, j = slot & 15, mlp = slot >> 4;
        const float* w1 = mlp ? rv_w1 : rm0_w1;
        if (bb < 32) {
            int a = bb * 8 + (t >> 5);
            const float* x = tgt_emb + (size_t)a * 128;
            const float* w = w1 + j * 416 + 32;
            float acc = 0.0f;
            for (int i = 0; i < 128; i += 4)
                acc = fmaf(x[i], w[i], fmaf(x[i+1], w[i+1], fmaf(x[i+2], w[i+2], fmaf(x[i+3], w[i+3], acc))));
            TA[a * 32 + slot] = acc;
        } else {
            int m = (bb - 32) * 8 + (t >> 5);
            const float* x = clus + (size_t)m * 2304;
            const float* w = w1 + j * 416 + 160;
            float acc = 0.0f;
            for (int i = 0; i < 256; i += 4)
                acc = fmaf(x[i], w[i], fmaf(x[i+1], w[i+1], fmaf(x[i+2], w[i+2], fmaf(x[i+3], w[i+3], acc))));
            CA[m * 32 + slot] = acc;
        }
    } else {
        int i = (b - 4448) * 256 + t;
        unsigned int w = mw[i];
        int vb = (w != 0u && w != 1u && w != 0x3F800000u) ? 1 : 0;
        int vf = (w == 0x3F800000u) ? 1 : 0;
        unsigned long long bal_b = __ballot(vb);
        unsigned long long bal_f = __ballot(vf);
        if ((t & 63) == 0) {
            if (bal_b) atomicOr(flag, 1);
            if (bal_f) atomicOr(flag, 2);
        }
    }
}

// ---------------- K2ab: fused edge pipeline (MFMA phase B) ----------------
__device__ __forceinline__ float lnsilu16(float x, float g, float b) {
    float s = x;
#pragma unroll
    for (int m = 1; m < 16; m <<= 1) s += __shfl_xor(s, m, 16);
    float mu = s * 0.0625f;
    float d = x - mu;
    float s2 = d * d;
#pragma unroll
    for (int m = 1; m < 16; m <<= 1) s2 += __shfl_xor(s2, m, 16);
    float y = d * rsqrtf(s2 * 0.0625f + 1e-5f) * g + b;
    return y * sigf(y);
}

__global__ __launch_bounds__(256, 2) void k2ab(
    const float* __restrict__ attn_weight, const void* __restrict__ mask,
    const int* __restrict__ mflag,
    const int* __restrict__ f_idx, const float* __restrict__ edge_vec,
    const int* __restrict__ atom_num,
    const float* __restrict__ q_ws, const unsigned short* __restrict__ keyh,
    const float* __restrict__ TA, const float* __restrict__ CA,
    const float* __restrict__ rm0_w1, const float* __restrict__ rm0_b1,
    const float* __restrict__ rm0_g1, const float* __restrict__ rm0_be1,
    const float* __restrict__ rm0_w2, const float* __restrict__ rm0_b2,
    const float* __restrict__ rm0_g2, const float* __restrict__ rm0_be2,
    const float* __restrict__ rm0_w3, const float* __restrict__ rm0_b3,
    const unsigned short* __restrict__ fcwh, const float* __restrict__ fcb,
    const float* __restrict__ an_g, const float* __restrict__ an_b,
    const float* __restrict__ alpha_dot,
    const float* __restrict__ rv_w1, const float* __restrict__ rv_b1,
    const float* __restrict__ rv_g1, const float* __restrict__ rv_be1,
    const float* __restrict__ rv_w2, const float* __restrict__ rv_b2,
    const float* __restrict__ rv_g2, const float* __restrict__ rv_be2,
    float* __restrict__ al_g, float* __restrict__ h2v_g)
{
    __shared__ float qn[288];
    __shared__ float Ts[32];
    __shared__ float shS[32][9];
    __shared__ __align__(16) unsigned char poolS[32 * 200 * 2];
    float (*awS)[32] = (float(*)[32])poolS;
    float (*caS)[32] = (float(*)[32])(poolS + 4096);
    unsigned short (*mwbS)[200] = (unsigned short(*)[200])poolS;
    __shared__ unsigned short KDSh[32][96];   // pre-dotted key (bf16)
    __shared__ float h2mS[32][17];
    __shared__ float lgS[32][8];
    __shared__ float mxS[8], invS[8];
    __shared__ int idxk[32], maskk[32];

    int n = blockIdx.x, t = threadIdx.x;
    int mode = mflag[0];

    for (int i = t; i < 288; i += 256) qn[i] = q_ws[(size_t)n * 288 + i];
    if (t < 32) {
        int an = atom_num[n];
        Ts[t] = TA[an * 32 + t];
        int e = n * KNBR + t;
        idxk[t] = f_idx[e];
        maskk[t] = edge_masked(mask, mode, e) ? 1 : 0;
        float vx = edge_vec[(size_t)e * 3 + 0];
        float vy = edge_vec[(size_t)e * 3 + 1];
        float vz = edge_vec[(size_t)e * 3 + 2];
        float inv = 1.0f / (sqrtf(vx * vx + vy * vy + vz * vz) + 1e-12f);
        float x = vx * inv, y = vy * inv, z = vz * inv;
        shS[t][0] = 0.28209479177387814f;
        shS[t][1] = 0.4886025119029199f * y;
        shS[t][2] = 0.4886025119029199f * z;
        shS[t][3] = 0.4886025119029199f * x;
        shS[t][4] = 1.0925484305920792f * x * y;
        shS[t][5] = 1.0925484305920792f * y * z;
        shS[t][6] = 0.31539156525252005f * (3.0f * z * z - 1.0f);
        shS[t][7] = 1.0925484305920792f * x * z;
        shS[t][8] = 0.5462742152960396f * (x * x - y * y);
    }
    __syncthreads();
    for (int e2 = t; e2 < 1024; e2 += 256) {
        int ek = e2 >> 5, i = e2 & 31;
        awS[ek][i] = maskk[ek] ? 0.0f : attn_weight[((size_t)(n * KNBR + ek)) * 32 + i];
        caS[ek][i] = CA[(size_t)idxk[ek] * 32 + i];
    }
    // stage pre-dotted key rows: KDSh[e][p*32+c] = bf16(<key_l, sh_l>)
    for (int i = t; i < 32 * 96; i += 256) {
        int e = i / 96, j = i - e * 96;
        int p = j >> 5, c = j & 31;
        const unsigned short* kr = keyh + (size_t)idxk[e] * 288;
        float v;
        if (p == 0)      v = bf2f(kr[c]) * shS[e][0];
        else if (p == 1) v = bf2f(kr[32 + c]) * shS[e][1] + bf2f(kr[64 + c]) * shS[e][2]
                           + bf2f(kr[96 + c]) * shS[e][3];
        else             v = bf2f(kr[128 + c]) * shS[e][4] + bf2f(kr[160 + c]) * shS[e][5]
                           + bf2f(kr[192 + c]) * shS[e][6] + bf2f(kr[224 + c]) * shS[e][7]
                           + bf2f(kr[256 + c]) * shS[e][8];
        KDSh[e][j] = f2bf(v);
    }
    __syncthreads();

    // ===== phase A: edge MLPs (wave-parallel, 16-lane groups) =====
    {
        int g = t >> 4, j = t & 15;
        for (int ee = 0; ee < 2; ++ee) {
            int e = g + ee * 16;
            float accm = rm0_b1[j] + Ts[j] + caS[e][j];
            float accv = rv_b1[j] + Ts[16 + j] + caS[e][16 + j];
            const float* w1m = rm0_w1 + j * 416;
            const float* w1v = rv_w1 + j * 416;
#pragma unroll
            for (int i = 0; i < 32; i += 4) {
                float a0 = awS[e][i], a1 = awS[e][i + 1], a2 = awS[e][i + 2], a3 = awS[e][i + 3];
                accm = fmaf(a0, w1m[i], fmaf(a1, w1m[i+1], fmaf(a2, w1m[i+2], fmaf(a3, w1m[i+3], accm))));
                accv = fmaf(a0, w1v[i], fmaf(a1, w1v[i+1], fmaf(a2, w1v[i+2], fmaf(a3, w1v[i+3], accv))));
            }
            float hm = lnsilu16(accm, rm0_g1[j], rm0_be1[j]);
            float hv = lnsilu16(accv, rv_g1[j], rv_be1[j]);
            float am2 = rm0_b2[j], av2 = rv_b2[j];
#pragma unroll
            for (int i = 0; i < 16; ++i) {
                am2 = fmaf(__shfl(hm, i, 16), rm0_w2[j * 16 + i], am2);
                av2 = fmaf(__shfl(hv, i, 16), rv_w2[j * 16 + i], av2);
            }
            float h2m = lnsilu16(am2, rm0_g2[j], rm0_be2[j]);
            float h2v = lnsilu16(av2, rv_g2[j], rv_be2[j]);
            h2v_g[(size_t)n * 512 + e * 16 + j] = h2v;
            h2mS[e][j] = h2m;
        }
    }
    __syncthreads();   // awS/caS dead from here; pool becomes mwbS

    // ===== phase M: mwb[e][d] = bf16((rm0 layer3) * m0), uniform bb =====
#pragma unroll
    for (int bb = 0; bb < 6; ++bb) {
#pragma unroll
        for (int r2 = 0; r2 < 4; ++r2) {
            int oi = r2 * 256 + t;          // 0..1023
            int e = oi >> 5, c = oi & 31;
            int d = bb * 32 + c;
            const float4* w3 = (const float4*)(rm0_w3 + d * 16);
            float ew = rm0_b3[d];
#pragma unroll
            for (int i4 = 0; i4 < 4; ++i4) {
                float4 w = w3[i4];
                ew = fmaf(h2mS[e][i4 * 4 + 0], w.x, fmaf(h2mS[e][i4 * 4 + 1], w.y,
                     fmaf(h2mS[e][i4 * 4 + 2], w.z, fmaf(h2mS[e][i4 * 4 + 3], w.w, ew))));
            }
            float m0v;
            if (bb == 0)      m0v = qn[c] * shS[e][0];
            else if (bb == 1) m0v = qn[32 + c] * shS[e][1] + qn[64 + c] * shS[e][2]
                                  + qn[96 + c] * shS[e][3];
            else if (bb == 2) m0v = qn[128 + c] * shS[e][4] + qn[160 + c] * shS[e][5]
                                  + qn[192 + c] * shS[e][6] + qn[224 + c] * shS[e][7]
                                  + qn[256 + c] * shS[e][8];
            else              m0v = bf2f(KDSh[e][(bb - 3) * 32 + c]);
            mwbS[e][d] = f2bf(ew * m0v);
        }
    }
    __syncthreads();

    // ===== phase B: af = mwa @ fcw^T + fcb via MFMA; LN + smooth_leaky + logits ===
    {
        int wid = t >> 6, lane = t & 63;
        int lrow = lane & 15, kgrp = lane >> 4;
        f32x4 acc[4][2];
#pragma unroll
        for (int i = 0; i < 4; ++i)
#pragma unroll
            for (int m = 0; m < 2; ++m) acc[i][m] = (f32x4){0.f, 0.f, 0.f, 0.f};

#pragma unroll
        for (int ntl = 0; ntl < 4; ++ntl) {
            int col = wid * 64 + ntl * 16 + lrow;
            const bf16x8* brow = (const bf16x8*)(fcwh + (size_t)col * 192);
            bf16x8 bf[6];
#pragma unroll
            for (int kk = 0; kk < 6; ++kk) bf[kk] = brow[kk * 4 + kgrp];
#pragma unroll
            for (int kk = 0; kk < 6; ++kk) {
#pragma unroll
                for (int m = 0; m < 2; ++m) {
                    bf16x8 a8 = *(const bf16x8*)&mwbS[m * 16 + lrow][kk * 32 + kgrp * 8];
                    acc[ntl][m] = __builtin_amdgcn_mfma_f32_16x16x32_bf16(a8, bf[kk], acc[ntl][m], 0, 0, 0);
                }
            }
        }
#pragma unroll
        for (int ntl = 0; ntl < 4; ++ntl) {
            float fb = fcb[wid * 64 + ntl * 16 + lrow];
#pragma unroll
            for (int m = 0; m < 2; ++m)
#pragma unroll
                for (int r = 0; r < 4; ++r) acc[ntl][m][r] += fb;
        }
        float ang0 = an_g[lrow], ang1 = an_g[16 + lrow];
        float anb0 = an_b[lrow], anb1 = an_b[16 + lrow];
#pragma unroll
        for (int hh = 0; hh < 2; ++hh) {
            int h = wid * 2 + hh;
            float ad0 = alpha_dot[h * 32 + lrow], ad1 = alpha_dot[h * 32 + 16 + lrow];
#pragma unroll
            for (int m = 0; m < 2; ++m) {
#pragma unroll
                for (int r = 0; r < 4; ++r) {
                    float a = acc[2 * hh][m][r], b = acc[2 * hh + 1][m][r];
                    float su = a + b;
#pragma unroll
                    for (int mm = 1; mm < 16; mm <<= 1) su += __shfl_xor(su, mm, 16);
                    float mu = su * (1.0f / 32.0f);
                    float da = a - mu, db = b - mu;
                    float v2 = da * da + db * db;
#pragma unroll
                    for (int mm = 1; mm < 16; mm <<= 1) v2 += __shfl_xor(v2, mm, 16);
                    float rs = rsqrtf(v2 * (1.0f / 32.0f) + 1e-5f);
                    float y0 = da * rs * ang0 + anb0;
                    float y1 = db * rs * ang1 + anb1;
                    float sl0 = 0.6f * y0 + 0.4f * y0 * (2.0f * sigf(y0) - 1.0f);
                    float sl1 = 0.6f * y1 + 0.4f * y1 * (2.0f * sigf(y1) - 1.0f);
                    float lg = sl0 * ad0 + sl1 * ad1;
#pragma unroll
                    for (int mm = 1; mm < 16; mm <<= 1) lg += __shfl_xor(lg, mm, 16);
                    if (lrow == 0) {
                        int e = m * 16 + kgrp * 4 + r;
                        lgS[e][h] = maskk[e] ? -1e9f : lg;
                    }
                }
            }
        }
    }
    __syncthreads();

    // ===== softmax over k, write alpha =====
    if (t < 8) {
        float mx = -1e30f;
#pragma unroll
        for (int k = 0; k < 32; ++k) mx = fmaxf(mx, lgS[k][t]);
        float sum = 0.0f;
#pragma unroll
        for (int k = 0; k < 32; ++k) sum += __expf(lgS[k][t] - mx);
        mxS[t] = mx;
        invS[t] = 1.0f / sum;
    }
    __syncthreads();
    {
        int k = t >> 3, h = t & 7;
        al_g[(size_t)n * 256 + t] = __expf(lgS[k][h] - mxS[h]) * invS[h];
    }
}

// ---------------- K2c: gather + aggregate (latency-bound, high-occupancy) --------
__global__ __launch_bounds__(256) void k2c(
    const float* __restrict__ al_g, const float* __restrict__ h2v_g,
    const int* __restrict__ f_idx, const unsigned short* __restrict__ clh,
    const float* __restrict__ rv_w3, const float* __restrict__ rv_b3,
    float* __restrict__ outpre)
{
    __shared__ float alS[256];        // [k][8]
    __shared__ float h2S[32][16];
    __shared__ int idxS[32];
    int n = blockIdx.x, t = threadIdx.x;
    alS[t] = al_g[(size_t)n * 256 + t];
    if (t < 32) idxS[t] = f_idx[n * KNBR + t];
    for (int i = t; i < 512; i += 256) h2S[i >> 4][i & 15] = h2v_g[(size_t)n * 512 + i];
    __syncthreads();

    int c = t, h = c >> 5;
    float avr[32];
    {
        float w3r[16];
        const float4* w3p = (const float4*)(rv_w3 + c * 16);
#pragma unroll
        for (int i4 = 0; i4 < 4; ++i4) {
            float4 w = w3p[i4];
            w3r[i4 * 4 + 0] = w.x; w3r[i4 * 4 + 1] = w.y;
            w3r[i4 * 4 + 2] = w.z; w3r[i4 * 4 + 3] = w.w;
        }
        float b3c = rv_b3[c];
#pragma unroll
        for (int k = 0; k < 32; ++k) {
            float vw = b3c;
#pragma unroll
            for (int i = 0; i < 16; ++i) vw = fmaf(h2S[k][i], w3r[i], vw);
            avr[k] = alS[k * 8 + h] * vw;
        }
    }

    float acc[9];
#pragma unroll
    for (int m = 0; m < 9; ++m) acc[m] = 0.0f;
#pragma unroll 4
    for (int k = 0; k < 32; ++k) {
        const unsigned short* crow = clh + (size_t)idxS[k] * 2304 + c;
        float av = avr[k];
#pragma unroll
        for (int m = 0; m < 9; ++m) acc[m] = fmaf(av, bf2f(crow[m * 256]), acc[m]);
    }
#pragma unroll
    for (int m = 0; m < 9; ++m) outpre[((size_t)n * 9 + m) * 256 + c] = acc[m];
}

// ---------------- K5: final so3_linear via MFMA (wzh bf16), in-place on d_out ----
__global__ __launch_bounds__(256) void k5_final(
    const unsigned short* __restrict__ wzh, const float* __restrict__ bz,
    float* __restrict__ io)
{
    __shared__ __align__(16) unsigned short Xb[32][264];
    __shared__ int rr[32];
    int b = blockIdx.x, t = threadIdx.x;
    int l, vr0, nm, moff;
    if (b < 64)       { l = 0; vr0 = b * 32;         nm = 1; moff = 0; }
    else if (b < 256) { l = 1; vr0 = (b - 64) * 32;  nm = 3; moff = 1; }
    else              { l = 2; vr0 = (b - 256) * 32; nm = 5; moff = 4; }
    if (t < 32) {
        int vr = vr0 + t;
        int n = vr / nm, m = moff + vr % nm;
        rr[t] = n * 9 + m;
    }
    __syncthreads();
    for (int e = t; e < 32 * 256; e += 256) {
        int r = e >> 8, c = e & 255;
        Xb[r][c] = f2bf(io[(size_t)rr[r] * 256 + c]);
    }
    __syncthreads();

    int wid = t >> 6, lane = t & 63;
    int lrow = lane & 15, kgrp = lane >> 4;
    f32x4 acc[2][4];
#pragma unroll
    for (int mt = 0; mt < 2; ++mt)
#pragma unroll
        for (int ntl = 0; ntl < 4; ++ntl) acc[mt][ntl] = (f32x4){0.f, 0.f, 0.f, 0.f};

#pragma unroll
    for (int ntl = 0; ntl < 4; ++ntl) {
        int dcol = wid * 64 + ntl * 16 + lrow;
        const bf16x8* brow = (const bf16x8*)(wzh + ((size_t)l * 256 + dcol) * 256);
#pragma unroll
        for (int kk = 0; kk < 8; ++kk) {
            bf16x8 b8 = brow[kk * 4 + kgrp];
#pragma unroll
            for (int mt = 0; mt < 2; ++mt) {
                bf16x8 a8 = *(const bf16x8*)&Xb[mt * 16 + lrow][kk * 32 + kgrp * 8];
                acc[mt][ntl] = __builtin_amdgcn_mfma_f32_16x16x32_bf16(a8, b8, acc[mt][ntl], 0, 0, 0);
            }
        }
    }
#pragma unroll
    for (int ntl = 0; ntl < 4; ++ntl) {
        int dcol = wid * 64 + ntl * 16 + lrow;
        float bias = (l == 0) ? bz[dcol] : 0.0f;
#pragma unroll
        for (int mt = 0; mt < 2; ++mt) {
#pragma unroll
            for (int r = 0; r < 4; ++r) {
                int row = mt * 16 + kgrp * 4 + r;
                io[(size_t)rr[row] * 256 + dcol] = acc[mt][ntl][r] + bias;
            }
        }
    }
}

// ---------------- launch ----------------
extern "C" void kernel_launch(void* const* d_in, const int* in_sizes, int n_in,
                              void* d_out, int out_size, void* d_ws, size_t ws_size,
                              hipStream_t stream)
{
    (void)in_sizes; (void)n_in; (void)out_size; (void)ws_size;

    const float* node_irreps = (const float*)d_in[1];
    const float* edge_vec    = (const float*)d_in[3];
    const float* attn_weight = (const float*)d_in[4];
    const int*   atom_num    = (const int*)d_in[5];
    const void*  attn_mask   = d_in[6];
    const int*   f_idx       = (const int*)d_in[7];
    const float* clus        = (const float*)d_in[8];
    const float* tgt_emb     = (const float*)d_in[9];
    const float* W_dot       = (const float*)d_in[10];
    const float* b_dot       = (const float*)d_in[11];
    const float* rm0_w1 = (const float*)d_in[12];
    const float* rm0_b1 = (const float*)d_in[13];
    const float* rm0_g1 = (const float*)d_in[14];
    const float* rm0_be1 = (const float*)d_in[15];
    const float* rm0_w2 = (const float*)d_in[16];
    const float* rm0_b2 = (const float*)d_in[17];
    const float* rm0_g2 = (const float*)d_in[18];
    const float* rm0_be2 = (const float*)d_in[19];
    const float* rm0_w3 = (const float*)d_in[20];
    const float* rm0_b3 = (const float*)d_in[21];
    const float* fcw = (const float*)d_in[22];
    const float* fcb = (const float*)d_in[23];
    const float* an_g = (const float*)d_in[24];
    const float* an_b = (const float*)d_in[25];
    const float* alpha_dot = (const float*)d_in[26];
    const float* rv_w1 = (const float*)d_in[27];
    const float* rv_b1 = (const float*)d_in[28];
    const float* rv_g1 = (const float*)d_in[29];
    const float* rv_be1 = (const float*)d_in[30];
    const float* rv_w2 = (const float*)d_in[31];
    const float* rv_b2 = (const float*)d_in[32];
    const float* rv_g2 = (const float*)d_in[33];
    const float* rv_be2 = (const float*)d_in[34];
    const float* rv_w3 = (const float*)d_in[35];
    const float* rv_b3 = (const float*)d_in[36];
    const float* wz = (const float*)d_in[37];
    const float* bz = (const float*)d_in[38];

    float* ws = (float*)d_ws;
    int* flag = (int*)d_ws;
    float* q_ws = ws + 16;                                                   // 2048*288 f32
    unsigned short* keyh = (unsigned short*)(q_ws + (size_t)NNODE * 288);    // 2048*288 bf16
    float* TA_ws = (float*)(keyh + (size_t)MCLUS * 288);                     // 256*32
    float* CA_ws = TA_ws + 256 * 32;                                         // 2048*32
    unsigned short* clh = (unsigned short*)(CA_ws + (size_t)MCLUS * 32);     // 2048*2304 bf16
    float* al_ws = (float*)(clh + (size_t)MCLUS * 2304);                     // 2048*256
    float* h2v_ws = al_ws + (size_t)NNODE * 256;                             // 2048*512
    unsigned short* fcwh = (unsigned short*)(h2v_ws + (size_t)NNODE * 512);  // 256*192 bf16
    unsigned short* wzh = fcwh + 256 * 192;                                  // 3*256*256 bf16
    float* outpre = (float*)d_out;

    hipMemsetAsync(flag, 0, sizeof(int), stream);
    kprep<<<4512, 256, 0, stream>>>(
        (const unsigned int*)attn_mask, flag,
        clus, fcw, wz, clh, fcwh, wzh,
        tgt_emb, rm0_w1, rv_w1, TA_ws, CA_ws,
        node_irreps, W_dot, b_dot, q_ws, keyh);
    k2ab<<<NNODE, 256, 0, stream>>>(
        attn_weight, attn_mask, flag, f_idx, edge_vec, atom_num,
        q_ws, keyh, TA_ws, CA_ws,
        rm0_w1, rm0_b1, rm0_g1, rm0_be1, rm0_w2, rm0_b2, rm0_g2, rm0_be2, rm0_w3, rm0_b3,
        fcwh, fcb, an_g, an_b, alpha_dot,
        rv_w1, rv_b1, rv_g1, rv_be1, rv_w2, rv_b2, rv_g2, rv_be2,
        al_ws, h2v_ws);
    k2c<<<NNODE, 256, 0, stream>>>(al_ws, h2v_ws, f_idx, clh, rv_w3, rv_b3, outpre);
    k5_final<<<576, 256, 0, stream>>>(wzh, bz, outpre);
}

// Round 16
// 201.742 us; speedup vs baseline: 1.2003x; 1.1296x over previous
//
#include <hip/hip_runtime.h>
#include <math.h>

#define NNODE 2048
#define MCLUS 2048
#define KNBR  32
#define CDIM  256
#define HHEAD 8

typedef __attribute__((ext_vector_type(8))) short bf16x8;
typedef __attribute__((ext_vector_type(4))) float f32x4;

__device__ __forceinline__ float sigf(float x) { return 1.0f / (1.0f + __expf(-x)); }

__device__ __forceinline__ unsigned short f2bf(float f) {
    unsigned x = __float_as_uint(f);
    unsigned r = ((x >> 16) & 1u) + 0x7FFFu;
    return (unsigned short)((x + r) >> 16);
}
__device__ __forceinline__ float bf2f(unsigned short u) {
    return __uint_as_float(((unsigned)u) << 16);
}

__device__ __forceinline__ bool edge_masked(const void* mp, int mode, int e) {
    if (mode & 2) return ((const float*)mp)[e] != 0.0f;
    if (mode & 1) return ((const unsigned char*)mp)[e] != 0;
    return ((const int*)mp)[e] != 0;
}

// ---------------- Kprep: fused k1 (MFMA so3 q/key) + kconv + kpre + k0 ----------
// blocks [0,1152): k1 ; [1152,4160): conv (2048 clus | 192 fcw | 768 wz) ;
// [4160,4448): kpre ; [4448,4512): k0 detect
__global__ __launch_bounds__(256) void kprep(
    const unsigned int* __restrict__ mw, int* __restrict__ flag,
    const float* __restrict__ clus, const float* __restrict__ fcw,
    const float* __restrict__ wz,
    unsigned short* __restrict__ clh, unsigned short* __restrict__ fcwh,
    unsigned short* __restrict__ wzh,
    const float* __restrict__ tgt_emb,
    const float* __restrict__ rm0_w1, const float* __restrict__ rv_w1,
    float* __restrict__ TA, float* __restrict__ CA,
    const float* __restrict__ nodei, const float* __restrict__ W_dot,
    const float* __restrict__ b_dot,
    float* __restrict__ q_ws, unsigned short* __restrict__ keyh)
{
    __shared__ __align__(16) unsigned short Xb[32][264];
    __shared__ __align__(16) unsigned short Wb[32][264];
    __shared__ int rx[32], rmm[32];
    int b = blockIdx.x, t = threadIdx.x;

    if (b < 1152) {
        // ---- k1: so3_linear via MFMA: out[32r][32d] = X[32][256] @ W_dot[l]^T ----
        int l, vr0, nm, moff;
        if (b < 128)      { l = 0; vr0 = b * 32;         nm = 1; moff = 0; }
        else if (b < 512) { l = 1; vr0 = (b - 128) * 32; nm = 3; moff = 1; }
        else              { l = 2; vr0 = (b - 512) * 32; nm = 5; moff = 4; }
        if (t < 32) {
            int vr = vr0 + t;
            rx[t] = vr / nm;
            rmm[t] = moff + vr % nm;
        }
        __syncthreads();
        for (int e = t; e < 32 * 256; e += 256) {
            int r = e >> 8, c = e & 255;
            int x = rx[r], m = rmm[r];
            const float* src = (x < NNODE) ? (nodei + ((size_t)x * 9 + m) * 256)
                                           : (clus + ((size_t)(x - NNODE) * 9 + m) * 256);
            Xb[r][c] = f2bf(src[c]);
            Wb[r][c] = f2bf(W_dot[((size_t)l * 32 + r) * 256 + c]);
        }
        __syncthreads();

        int wid = t >> 6, lane = t & 63;
        int lrow = lane & 15, kgrp = lane >> 4;
        int mt = wid >> 1, nt = wid & 1;
        f32x4 acc = (f32x4){0.f, 0.f, 0.f, 0.f};
#pragma unroll
        for (int kk = 0; kk < 8; ++kk) {
            bf16x8 a8 = *(const bf16x8*)&Xb[mt * 16 + lrow][kk * 32 + kgrp * 8];
            bf16x8 b8 = *(const bf16x8*)&Wb[nt * 16 + lrow][kk * 32 + kgrp * 8];
            acc = __builtin_amdgcn_mfma_f32_16x16x32_bf16(a8, b8, acc, 0, 0, 0);
        }
        int dcol = nt * 16 + lrow;
        float bias = (l == 0) ? b_dot[dcol] : 0.0f;
#pragma unroll
        for (int r = 0; r < 4; ++r) {
            int row = mt * 16 + kgrp * 4 + r;
            int x = rx[row], m = rmm[row];
            float val = acc[r] + bias;
            if (x < NNODE) q_ws[((size_t)x * 9 + m) * 32 + dcol] = val;
            else           keyh[((size_t)(x - NNODE) * 9 + m) * 32 + dcol] = f2bf(val);
        }
    } else if (b < 4160) {
        int bb = b - 1152;
        if (bb < MCLUS) {
            size_t base = (size_t)bb * 2304;
#pragma unroll
            for (int r = 0; r < 9; ++r) {
                int o = r * 256 + t;
                clh[base + o] = f2bf(clus[base + o]);
            }
        } else if (bb < MCLUS + 192) {
            int off = (bb - MCLUS) * 256 + t;
            fcwh[off] = f2bf(fcw[off]);
        } else {
            int off = (bb - MCLUS - 192) * 256 + t;
            wzh[off] = f2bf(wz[off]);
        }
    } else if (b < 4448) {
        int bb = b - 4160;
        int slot = t & 31, j = slot & 15, mlp = slot >> 4;
        const float* w1 = mlp ? rv_w1 : rm0_w1;
        if (bb < 32) {
            int a = bb * 8 + (t >> 5);
            const float* x = tgt_emb + (size_t)a * 128;
            const float* w = w1 + j * 416 + 32;
            float acc = 0.0f;
            for (int i = 0; i < 128; i += 4)
                acc = fmaf(x[i], w[i], fmaf(x[i+1], w[i+1], fmaf(x[i+2], w[i+2], fmaf(x[i+3], w[i+3], acc))));
            TA[a * 32 + slot] = acc;
        } else {
            int m = (bb - 32) * 8 + (t >> 5);
            const float* x = clus + (size_t)m * 2304;
            const float* w = w1 + j * 416 + 160;
            float acc = 0.0f;
            for (int i = 0; i < 256; i += 4)
                acc = fmaf(x[i], w[i], fmaf(x[i+1], w[i+1], fmaf(x[i+2], w[i+2], fmaf(x[i+3], w[i+3], acc))));
            CA[m * 32 + slot] = acc;
        }
    } else {
        int i = (b - 4448) * 256 + t;
        unsigned int w = mw[i];
        int vb = (w != 0u && w != 1u && w != 0x3F800000u) ? 1 : 0;
        int vf = (w == 0x3F800000u) ? 1 : 0;
        unsigned long long bal_b = __ballot(vb);
        unsigned long long bal_f = __ballot(vf);
        if ((t & 63) == 0) {
            if (bal_b) atomicOr(flag, 1);
            if (bal_f) atomicOr(flag, 2);
        }
    }
}

// ---------------- K2ab: fused edge pipeline (MFMA phase B) ----------------
__device__ __forceinline__ float lnsilu16(float x, float g, float b) {
    float s = x;
#pragma unroll
    for (int m = 1; m < 16; m <<= 1) s += __shfl_xor(s, m, 16);
    float mu = s * 0.0625f;
    float d = x - mu;
    float s2 = d * d;
#pragma unroll
    for (int m = 1; m < 16; m <<= 1) s2 += __shfl_xor(s2, m, 16);
    float y = d * rsqrtf(s2 * 0.0625f + 1e-5f) * g + b;
    return y * sigf(y);
}

__global__ __launch_bounds__(256, 2) void k2ab(
    const float* __restrict__ attn_weight, const void* __restrict__ mask,
    const int* __restrict__ mflag,
    const int* __restrict__ f_idx, const float* __restrict__ edge_vec,
    const int* __restrict__ atom_num,
    const float* __restrict__ q_ws, const unsigned short* __restrict__ keyh,
    const float* __restrict__ TA, const float* __restrict__ CA,
    const float* __restrict__ rm0_w1, const float* __restrict__ rm0_b1,
    const float* __restrict__ rm0_g1, const float* __restrict__ rm0_be1,
    const float* __restrict__ rm0_w2, const float* __restrict__ rm0_b2,
    const float* __restrict__ rm0_g2, const float* __restrict__ rm0_be2,
    const float* __restrict__ rm0_w3, const float* __restrict__ rm0_b3,
    const unsigned short* __restrict__ fcwh, const float* __restrict__ fcb,
    const float* __restrict__ an_g, const float* __restrict__ an_b,
    const float* __restrict__ alpha_dot,
    const float* __restrict__ rv_w1, const float* __restrict__ rv_b1,
    const float* __restrict__ rv_g1, const float* __restrict__ rv_be1,
    const float* __restrict__ rv_w2, const float* __restrict__ rv_b2,
    const float* __restrict__ rv_g2, const float* __restrict__ rv_be2,
    float* __restrict__ al_g, float* __restrict__ h2v_g)
{
    __shared__ float qn[288];
    __shared__ float Ts[32];
    __shared__ float shS[32][9];
    __shared__ __align__(16) unsigned char poolS[32 * 200 * 2];
    float (*awS)[32] = (float(*)[32])poolS;
    float (*caS)[32] = (float(*)[32])(poolS + 4096);
    unsigned short (*mwbS)[200] = (unsigned short(*)[200])poolS;
    __shared__ unsigned short KDSh[32][96];   // pre-dotted key (bf16)
    __shared__ float h2mS[32][17];
    __shared__ float lgS[32][8];
    __shared__ float mxS[8], invS[8];
    __shared__ int idxk[32], maskk[32];

    int n = blockIdx.x, t = threadIdx.x;
    int mode = mflag[0];

    for (int i = t; i < 288; i += 256) qn[i] = q_ws[(size_t)n * 288 + i];
    if (t < 32) {
        int an = atom_num[n];
        Ts[t] = TA[an * 32 + t];
        int e = n * KNBR + t;
        idxk[t] = f_idx[e];
        maskk[t] = edge_masked(mask, mode, e) ? 1 : 0;
        float vx = edge_vec[(size_t)e * 3 + 0];
        float vy = edge_vec[(size_t)e * 3 + 1];
        float vz = edge_vec[(size_t)e * 3 + 2];
        float inv = 1.0f / (sqrtf(vx * vx + vy * vy + vz * vz) + 1e-12f);
        float x = vx * inv, y = vy * inv, z = vz * inv;
        shS[t][0] = 0.28209479177387814f;
        shS[t][1] = 0.4886025119029199f * y;
        shS[t][2] = 0.4886025119029199f * z;
        shS[t][3] = 0.4886025119029199f * x;
        shS[t][4] = 1.0925484305920792f * x * y;
        shS[t][5] = 1.0925484305920792f * y * z;
        shS[t][6] = 0.31539156525252005f * (3.0f * z * z - 1.0f);
        shS[t][7] = 1.0925484305920792f * x * z;
        shS[t][8] = 0.5462742152960396f * (x * x - y * y);
    }
    __syncthreads();
    for (int e2 = t; e2 < 1024; e2 += 256) {
        int ek = e2 >> 5, i = e2 & 31;
        awS[ek][i] = maskk[ek] ? 0.0f : attn_weight[((size_t)(n * KNBR + ek)) * 32 + i];
        caS[ek][i] = CA[(size_t)idxk[ek] * 32 + i];
    }
    // stage pre-dotted key rows: KDSh[e][p*32+c] = bf16(<key_l, sh_l>)
    for (int i = t; i < 32 * 96; i += 256) {
        int e = i / 96, j = i - e * 96;
        int p = j >> 5, c = j & 31;
        const unsigned short* kr = keyh + (size_t)idxk[e] * 288;
        float v;
        if (p == 0)      v = bf2f(kr[c]) * shS[e][0];
        else if (p == 1) v = bf2f(kr[32 + c]) * shS[e][1] + bf2f(kr[64 + c]) * shS[e][2]
                           + bf2f(kr[96 + c]) * shS[e][3];
        else             v = bf2f(kr[128 + c]) * shS[e][4] + bf2f(kr[160 + c]) * shS[e][5]
                           + bf2f(kr[192 + c]) * shS[e][6] + bf2f(kr[224 + c]) * shS[e][7]
                           + bf2f(kr[256 + c]) * shS[e][8];
        KDSh[e][j] = f2bf(v);
    }
    __syncthreads();

    // ===== phase A: edge MLPs (wave-parallel, 16-lane groups) =====
    {
        int g = t >> 4, j = t & 15;
        for (int ee = 0; ee < 2; ++ee) {
            int e = g + ee * 16;
            float accm = rm0_b1[j] + Ts[j] + caS[e][j];
            float accv = rv_b1[j] + Ts[16 + j] + caS[e][16 + j];
            const float* w1m = rm0_w1 + j * 416;
            const float* w1v = rv_w1 + j * 416;
#pragma unroll
            for (int i = 0; i < 32; i += 4) {
                float a0 = awS[e][i], a1 = awS[e][i + 1], a2 = awS[e][i + 2], a3 = awS[e][i + 3];
                accm = fmaf(a0, w1m[i], fmaf(a1, w1m[i+1], fmaf(a2, w1m[i+2], fmaf(a3, w1m[i+3], accm))));
                accv = fmaf(a0, w1v[i], fmaf(a1, w1v[i+1], fmaf(a2, w1v[i+2], fmaf(a3, w1v[i+3], accv))));
            }
            float hm = lnsilu16(accm, rm0_g1[j], rm0_be1[j]);
            float hv = lnsilu16(accv, rv_g1[j], rv_be1[j]);
            float am2 = rm0_b2[j], av2 = rv_b2[j];
#pragma unroll
            for (int i = 0; i < 16; ++i) {
                am2 = fmaf(__shfl(hm, i, 16), rm0_w2[j * 16 + i], am2);
                av2 = fmaf(__shfl(hv, i, 16), rv_w2[j * 16 + i], av2);
            }
            float h2m = lnsilu16(am2, rm0_g2[j], rm0_be2[j]);
            float h2v = lnsilu16(av2, rv_g2[j], rv_be2[j]);
            h2v_g[(size_t)n * 512 + e * 16 + j] = h2v;
            h2mS[e][j] = h2m;
        }
    }
    __syncthreads();   // awS/caS dead from here; pool becomes mwbS

    // ===== phase M: mwb[e][d] = bf16((rm0 layer3) * m0), uniform bb =====
#pragma unroll
    for (int bb = 0; bb < 6; ++bb) {
#pragma unroll
        for (int r2 = 0; r2 < 4; ++r2) {
            int oi = r2 * 256 + t;          // 0..1023
            int e = oi >> 5, c = oi & 31;
            int d = bb * 32 + c;
            const float4* w3 = (const float4*)(rm0_w3 + d * 16);
            float ew = rm0_b3[d];
#pragma unroll
            for (int i4 = 0; i4 < 4; ++i4) {
                float4 w = w3[i4];
                ew = fmaf(h2mS[e][i4 * 4 + 0], w.x, fmaf(h2mS[e][i4 * 4 + 1], w.y,
                     fmaf(h2mS[e][i4 * 4 + 2], w.z, fmaf(h2mS[e][i4 * 4 + 3], w.w, ew))));
            }
            float m0v;
            if (bb == 0)      m0v = qn[c] * shS[e][0];
            else if (bb == 1) m0v = qn[32 + c] * shS[e][1] + qn[64 + c] * shS[e][2]
                                  + qn[96 + c] * shS[e][3];
            else if (bb == 2) m0v = qn[128 + c] * shS[e][4] + qn[160 + c] * shS[e][5]
                                  + qn[192 + c] * shS[e][6] + qn[224 + c] * shS[e][7]
                                  + qn[256 + c] * shS[e][8];
            else              m0v = bf2f(KDSh[e][(bb - 3) * 32 + c]);
            mwbS[e][d] = f2bf(ew * m0v);
        }
    }
    __syncthreads();

    // ===== phase B: af = mwa @ fcw^T + fcb via MFMA; LN + smooth_leaky + logits ===
    {
        int wid = t >> 6, lane = t & 63;
        int lrow = lane & 15, kgrp = lane >> 4;
        f32x4 acc[4][2];
#pragma unroll
        for (int i = 0; i < 4; ++i)
#pragma unroll
            for (int m = 0; m < 2; ++m) acc[i][m] = (f32x4){0.f, 0.f, 0.f, 0.f};

#pragma unroll
        for (int ntl = 0; ntl < 4; ++ntl) {
            int col = wid * 64 + ntl * 16 + lrow;
            const bf16x8* brow = (const bf16x8*)(fcwh + (size_t)col * 192);
            bf16x8 bf[6];
#pragma unroll
            for (int kk = 0; kk < 6; ++kk) bf[kk] = brow[kk * 4 + kgrp];
#pragma unroll
            for (int kk = 0; kk < 6; ++kk) {
#pragma unroll
                for (int m = 0; m < 2; ++m) {
                    bf16x8 a8 = *(const bf16x8*)&mwbS[m * 16 + lrow][kk * 32 + kgrp * 8];
                    acc[ntl][m] = __builtin_amdgcn_mfma_f32_16x16x32_bf16(a8, bf[kk], acc[ntl][m], 0, 0, 0);
                }
            }
        }
#pragma unroll
        for (int ntl = 0; ntl < 4; ++ntl) {
            float fb = fcb[wid * 64 + ntl * 16 + lrow];
#pragma unroll
            for (int m = 0; m < 2; ++m)
#pragma unroll
                for (int r = 0; r < 4; ++r) acc[ntl][m][r] += fb;
        }
        float ang0 = an_g[lrow], ang1 = an_g[16 + lrow];
        float anb0 = an_b[lrow], anb1 = an_b[16 + lrow];
#pragma unroll
        for (int hh = 0; hh < 2; ++hh) {
            int h = wid * 2 + hh;
            float ad0 = alpha_dot[h * 32 + lrow], ad1 = alpha_dot[h * 32 + 16 + lrow];
#pragma unroll
            for (int m = 0; m < 2; ++m) {
#pragma unroll
                for (int r = 0; r < 4; ++r) {
                    float a = acc[2 * hh][m][r], b = acc[2 * hh + 1][m][r];
                    float su = a + b;
#pragma unroll
                    for (int mm = 1; mm < 16; mm <<= 1) su += __shfl_xor(su, mm, 16);
                    float mu = su * (1.0f / 32.0f);
                    float da = a - mu, db = b - mu;
                    float v2 = da * da + db * db;
#pragma unroll
                    for (int mm = 1; mm < 16; mm <<= 1) v2 += __shfl_xor(v2, mm, 16);
                    float rs = rsqrtf(v2 * (1.0f / 32.0f) + 1e-5f);
                    float y0 = da * rs * ang0 + anb0;
                    float y1 = db * rs * ang1 + anb1;
                    float sl0 = 0.6f * y0 + 0.4f * y0 * (2.0f * sigf(y0) - 1.0f);
                    float sl1 = 0.6f * y1 + 0.4f * y1 * (2.0f * sigf(y1) - 1.0f);
                    float lg = sl0 * ad0 + sl1 * ad1;
#pragma unroll
                    for (int mm = 1; mm < 16; mm <<= 1) lg += __shfl_xor(lg, mm, 16);
                    if (lrow == 0) {
                        int e = m * 16 + kgrp * 4 + r;
                        lgS[e][h] = maskk[e] ? -1e9f : lg;
                    }
                }
            }
        }
    }
    __syncthreads();

    // ===== softmax over k, write alpha =====
    if (t < 8) {
        float mx = -1e30f;
#pragma unroll
        for (int k = 0; k < 32; ++k) mx = fmaxf(mx, lgS[k][t]);
        float sum = 0.0f;
#pragma unroll
        for (int k = 0; k < 32; ++k) sum += __expf(lgS[k][t] - mx);
        mxS[t] = mx;
        invS[t] = 1.0f / sum;
    }
    __syncthreads();
    {
        int k = t >> 3, h = t & 7;
        al_g[(size_t)n * 256 + t] = __expf(lgS[k][h] - mxS[h]) * invS[h];
    }
}

// ---------------- K2c: gather + aggregate (latency-bound, high-occupancy) --------
__global__ __launch_bounds__(256) void k2c(
    const float* __restrict__ al_g, const float* __restrict__ h2v_g,
    const int* __restrict__ f_idx, const unsigned short* __restrict__ clh,
    const float* __restrict__ rv_w3, const float* __restrict__ rv_b3,
    float* __restrict__ outpre)
{
    __shared__ float alS[256];        // [k][8]
    __shared__ float h2S[32][16];
    __shared__ int idxS[32];
    int n = blockIdx.x, t = threadIdx.x;
    alS[t] = al_g[(size_t)n * 256 + t];
    if (t < 32) idxS[t] = f_idx[n * KNBR + t];
    for (int i = t; i < 512; i += 256) h2S[i >> 4][i & 15] = h2v_g[(size_t)n * 512 + i];
    __syncthreads();

    int c = t, h = c >> 5;
    float avr[32];
    {
        float w3r[16];
        const float4* w3p = (const float4*)(rv_w3 + c * 16);
#pragma unroll
        for (int i4 = 0; i4 < 4; ++i4) {
            float4 w = w3p[i4];
            w3r[i4 * 4 + 0] = w.x; w3r[i4 * 4 + 1] = w.y;
            w3r[i4 * 4 + 2] = w.z; w3r[i4 * 4 + 3] = w.w;
        }
        float b3c = rv_b3[c];
#pragma unroll
        for (int k = 0; k < 32; ++k) {
            float vw = b3c;
#pragma unroll
            for (int i = 0; i < 16; ++i) vw = fmaf(h2S[k][i], w3r[i], vw);
            avr[k] = alS[k * 8 + h] * vw;
        }
    }

    float acc[9];
#pragma unroll
    for (int m = 0; m < 9; ++m) acc[m] = 0.0f;
#pragma unroll 4
    for (int k = 0; k < 32; ++k) {
        const unsigned short* crow = clh + (size_t)idxS[k] * 2304 + c;
        float av = avr[k];
#pragma unroll
        for (int m = 0; m < 9; ++m) acc[m] = fmaf(av, bf2f(crow[m * 256]), acc[m]);
    }
#pragma unroll
    for (int m = 0; m < 9; ++m) outpre[((size_t)n * 9 + m) * 256 + c] = acc[m];
}

// ---------------- K5: final so3_linear via MFMA (wzh bf16), in-place on d_out ----
__global__ __launch_bounds__(256) void k5_final(
    const unsigned short* __restrict__ wzh, const float* __restrict__ bz,
    float* __restrict__ io)
{
    __shared__ __align__(16) unsigned short Xb[32][264];
    __shared__ int rr[32];
    int b = blockIdx.x, t = threadIdx.x;
    int l, vr0, nm, moff;
    if (b < 64)       { l = 0; vr0 = b * 32;         nm = 1; moff = 0; }
    else if (b < 256) { l = 1; vr0 = (b - 64) * 32;  nm = 3; moff = 1; }
    else              { l = 2; vr0 = (b - 256) * 32; nm = 5; moff = 4; }
    if (t < 32) {
        int vr = vr0 + t;
        int n = vr / nm, m = moff + vr % nm;
        rr[t] = n * 9 + m;
    }
    __syncthreads();
    for (int e = t; e < 32 * 256; e += 256) {
        int r = e >> 8, c = e & 255;
        Xb[r][c] = f2bf(io[(size_t)rr[r] * 256 + c]);
    }
    __syncthreads();

    int wid = t >> 6, lane = t & 63;
    int lrow = lane & 15, kgrp = lane >> 4;
    f32x4 acc[2][4];
#pragma unroll
    for (int mt = 0; mt < 2; ++mt)
#pragma unroll
        for (int ntl = 0; ntl < 4; ++ntl) acc[mt][ntl] = (f32x4){0.f, 0.f, 0.f, 0.f};

#pragma unroll
    for (int ntl = 0; ntl < 4; ++ntl) {
        int dcol = wid * 64 + ntl * 16 + lrow;
        const bf16x8* brow = (const bf16x8*)(wzh + ((size_t)l * 256 + dcol) * 256);
#pragma unroll
        for (int kk = 0; kk < 8; ++kk) {
            bf16x8 b8 = brow[kk * 4 + kgrp];
#pragma unroll
            for (int mt = 0; mt < 2; ++mt) {
                bf16x8 a8 = *(const bf16x8*)&Xb[mt * 16 + lrow][kk * 32 + kgrp * 8];
                acc[mt][ntl] = __builtin_amdgcn_mfma_f32_16x16x32_bf16(a8, b8, acc[mt][ntl], 0, 0, 0);
            }
        }
    }
#pragma unroll
    for (int ntl = 0; ntl < 4; ++ntl) {
        int dcol = wid * 64 + ntl * 16 + lrow;
        float bias = (l == 0) ? bz[dcol] : 0.0f;
#pragma unroll
        for (int mt = 0; mt < 2; ++mt) {
#pragma unroll
            for (int r = 0; r < 4; ++r) {
                int row = mt * 16 + kgrp * 4 + r;
                io[(size_t)rr[row] * 256 + dcol] = acc[mt][ntl][r] + bias;
            }
        }
    }
}

// ---------------- launch ----------------
extern "C" void kernel_launch(void* const* d_in, const int* in_sizes, int n_in,
                              void* d_out, int out_size, void* d_ws, size_t ws_size,
                              hipStream_t stream)
{
    (void)in_sizes; (void)n_in; (void)out_size; (void)ws_size;

    const float* node_irreps = (const float*)d_in[1];
    const float* edge_vec    = (const float*)d_in[3];
    const float* attn_weight = (const float*)d_in[4];
    const int*   atom_num    = (const int*)d_in[5];
    const void*  attn_mask   = d_in[6];
    const int*   f_idx       = (const int*)d_in[7];
    const float* clus        = (const float*)d_in[8];
    const float* tgt_emb     = (const float*)d_in[9];
    const float* W_dot       = (const float*)d_in[10];
    const float* b_dot       = (const float*)d_in[11];
    const float* rm0_w1 = (const float*)d_in[12];
    const float* rm0_b1 = (const float*)d_in[13];
    const float* rm0_g1 = (const float*)d_in[14];
    const float* rm0_be1 = (const float*)d_in[15];
    const float* rm0_w2 = (const float*)d_in[16];
    const float* rm0_b2 = (const float*)d_in[17];
    const float* rm0_g2 = (const float*)d_in[18];
    const float* rm0_be2 = (const float*)d_in[19];
    const float* rm0_w3 = (const float*)d_in[20];
    const float* rm0_b3 = (const float*)d_in[21];
    const float* fcw = (const float*)d_in[22];
    const float* fcb = (const float*)d_in[23];
    const float* an_g = (const float*)d_in[24];
    const float* an_b = (const float*)d_in[25];
    const float* alpha_dot = (const float*)d_in[26];
    const float* rv_w1 = (const float*)d_in[27];
    const float* rv_b1 = (const float*)d_in[28];
    const float* rv_g1 = (const float*)d_in[29];
    const float* rv_be1 = (const float*)d_in[30];
    const float* rv_w2 = (const float*)d_in[31];
    const float* rv_b2 = (const float*)d_in[32];
    const float* rv_g2 = (const float*)d_in[33];
    const float* rv_be2 = (const float*)d_in[34];
    const float* rv_w3 = (const float*)d_in[35];
    const float* rv_b3 = (const float*)d_in[36];
    const float* wz = (const float*)d_in[37];
    const float* bz = (const float*)d_in[38];

    float* ws = (float*)d_ws;
    int* flag = (int*)d_ws;
    float* q_ws = ws + 16;                                                   // 2048*288 f32
    unsigned short* keyh = (unsigned short*)(q_ws + (size_t)NNODE * 288);    // 2048*288 bf16
    float* TA_ws = (float*)(keyh + (size_t)MCLUS * 288);                     // 256*32
    float* CA_ws = TA_ws + 256 * 32;                                         // 2048*32
    unsigned short* clh = (unsigned short*)(CA_ws + (size_t)MCLUS * 32);     // 2048*2304 bf16
    float* al_ws = (float*)(clh + (size_t)MCLUS * 2304);                     // 2048*256
    float* h2v_ws = al_ws + (size_t)NNODE * 256;                             // 2048*512
    unsigned short* fcwh = (unsigned short*)(h2v_ws + (size_t)NNODE * 512);  // 256*192 bf16
    unsigned short* wzh = fcwh + 256 * 192;                                  // 3*256*256 bf16
    float* outpre = (float*)d_out;

    hipMemsetAsync(flag, 0, sizeof(int), stream);
    kprep<<<4512, 256, 0, stream>>>(
        (const unsigned int*)attn_mask, flag,
        clus, fcw, wz, clh, fcwh, wzh,
        tgt_emb, rm0_w1, rv_w1, TA_ws, CA_ws,
        node_irreps, W_dot, b_dot, q_ws, keyh);
    k2ab<<<NNODE, 256, 0, stream>>>(
        attn_weight, attn_mask, flag, f_idx, edge_vec, atom_num,
        q_ws, keyh, TA_ws, CA_ws,
        rm0_w1, rm0_b1, rm0_g1, rm0_be1, rm0_w2, rm0_b2, rm0_g2, rm0_be2, rm0_w3, rm0_b3,
        fcwh, fcb, an_g, an_b, alpha_dot,
        rv_w1, rv_b1, rv_g1, rv_be1, rv_w2, rv_b2, rv_g2, rv_be2,
        al_ws, h2v_ws);
    k2c<<<NNODE, 256, 0, stream>>>(al_ws, h2v_ws, f_idx, clh, rv_w3, rv_b3, outpre);
    k5_final<<<576, 256, 0, stream>>>(wzh, bz, outpre);
}

// Round 17
// 198.707 us; speedup vs baseline: 1.2186x; 1.0153x over previous
//
#include <hip/hip_runtime.h>
#include <math.h>

#define NNODE 2048
#define MCLUS 2048
#define KNBR  32
#define CDIM  256
#define HHEAD 8

typedef __attribute__((ext_vector_type(8))) short bf16x8;
typedef __attribute__((ext_vector_type(4))) float f32x4;

__device__ __forceinline__ float sigf(float x) { return 1.0f / (1.0f + __expf(-x)); }

__device__ __forceinline__ unsigned short f2bf(float f) {
    unsigned x = __float_as_uint(f);
    unsigned r = ((x >> 16) & 1u) + 0x7FFFu;
    return (unsigned short)((x + r) >> 16);
}
__device__ __forceinline__ float bf2f(unsigned short u) {
    return __uint_as_float(((unsigned)u) << 16);
}

__device__ __forceinline__ bool edge_masked(const void* mp, int mode, int e) {
    if (mode & 2) return ((const float*)mp)[e] != 0.0f;
    if (mode & 1) return ((const unsigned char*)mp)[e] != 0;
    return ((const int*)mp)[e] != 0;
}

// ---------------- Kprep: fused k1 (MFMA so3 q/key) + kconv + kpre + k0 ----------
__global__ __launch_bounds__(256) void kprep(
    const unsigned int* __restrict__ mw, int* __restrict__ flag,
    const float* __restrict__ clus, const float* __restrict__ fcw,
    const float* __restrict__ wz,
    unsigned short* __restrict__ clh, unsigned short* __restrict__ fcwh,
    unsigned short* __restrict__ wzh,
    const float* __restrict__ tgt_emb,
    const float* __restrict__ rm0_w1, const float* __restrict__ rv_w1,
    float* __restrict__ TA, float* __restrict__ CA,
    const float* __restrict__ nodei, const float* __restrict__ W_dot,
    const float* __restrict__ b_dot,
    float* __restrict__ q_ws, unsigned short* __restrict__ keyh)
{
    __shared__ __align__(16) unsigned short Xb[32][264];
    __shared__ __align__(16) unsigned short Wb[32][264];
    __shared__ int rx[32], rmm[32];
    int b = blockIdx.x, t = threadIdx.x;

    if (b < 1152) {
        int l, vr0, nm, moff;
        if (b < 128)      { l = 0; vr0 = b * 32;         nm = 1; moff = 0; }
        else if (b < 512) { l = 1; vr0 = (b - 128) * 32; nm = 3; moff = 1; }
        else              { l = 2; vr0 = (b - 512) * 32; nm = 5; moff = 4; }
        if (t < 32) {
            int vr = vr0 + t;
            rx[t] = vr / nm;
            rmm[t] = moff + vr % nm;
        }
        __syncthreads();
        for (int e = t; e < 32 * 256; e += 256) {
            int r = e >> 8, c = e & 255;
            int x = rx[r], m = rmm[r];
            const float* src = (x < NNODE) ? (nodei + ((size_t)x * 9 + m) * 256)
                                           : (clus + ((size_t)(x - NNODE) * 9 + m) * 256);
            Xb[r][c] = f2bf(src[c]);
            Wb[r][c] = f2bf(W_dot[((size_t)l * 32 + r) * 256 + c]);
        }
        __syncthreads();

        int wid = t >> 6, lane = t & 63;
        int lrow = lane & 15, kgrp = lane >> 4;
        int mt = wid >> 1, nt = wid & 1;
        f32x4 acc = (f32x4){0.f, 0.f, 0.f, 0.f};
#pragma unroll
        for (int kk = 0; kk < 8; ++kk) {
            bf16x8 a8 = *(const bf16x8*)&Xb[mt * 16 + lrow][kk * 32 + kgrp * 8];
            bf16x8 b8 = *(const bf16x8*)&Wb[nt * 16 + lrow][kk * 32 + kgrp * 8];
            acc = __builtin_amdgcn_mfma_f32_16x16x32_bf16(a8, b8, acc, 0, 0, 0);
        }
        int dcol = nt * 16 + lrow;
        float bias = (l == 0) ? b_dot[dcol] : 0.0f;
#pragma unroll
        for (int r = 0; r < 4; ++r) {
            int row = mt * 16 + kgrp * 4 + r;
            int x = rx[row], m = rmm[row];
            float val = acc[r] + bias;
            if (x < NNODE) q_ws[((size_t)x * 9 + m) * 32 + dcol] = val;
            else           keyh[((size_t)(x - NNODE) * 9 + m) * 32 + dcol] = f2bf(val);
        }
    } else if (b < 4160) {
        int bb = b - 1152;
        if (bb < MCLUS) {
            size_t base = (size_t)bb * 2304;
#pragma unroll
            for (int r = 0; r < 9; ++r) {
                int o = r * 256 + t;
                clh[base + o] = f2bf(clus[base + o]);
            }
        } else if (bb < MCLUS + 192) {
            int off = (bb - MCLUS) * 256 + t;
            fcwh[off] = f2bf(fcw[off]);
        } else {
            int off = (bb - MCLUS - 192) * 256 + t;
            wzh[off] = f2bf(wz[off]);
        }
    } else if (b < 4448) {
        int bb = b - 4160;
        int slot = t & 31, j = slot & 15, mlp = slot >> 4;
        const float* w1 = mlp ? rv_w1 : rm0_w1;
        if (bb < 32) {
            int a = bb * 8 + (t >> 5);
            const float* x = tgt_emb + (size_t)a * 128;
            const float* w = w1 + j * 416 + 32;
            float acc = 0.0f;
            for (int i = 0; i < 128; i += 4)
                acc = fmaf(x[i], w[i], fmaf(x[i+1], w[i+1], fmaf(x[i+2], w[i+2], fmaf(x[i+3], w[i+3], acc))));
            TA[a * 32 + slot] = acc;
        } else {
            int m = (bb - 32) * 8 + (t >> 5);
            const float* x = clus + (size_t)m * 2304;
            const float* w = w1 + j * 416 + 160;
            float acc = 0.0f;
            for (int i = 0; i < 256; i += 4)
                acc = fmaf(x[i], w[i], fmaf(x[i+1], w[i+1], fmaf(x[i+2], w[i+2], fmaf(x[i+3], w[i+3], acc))));
            CA[m * 32 + slot] = acc;
        }
    } else {
        int i = (b - 4448) * 256 + t;
        unsigned int w = mw[i];
        int vb = (w != 0u && w != 1u && w != 0x3F800000u) ? 1 : 0;
        int vf = (w == 0x3F800000u) ? 1 : 0;
        unsigned long long bal_b = __ballot(vb);
        unsigned long long bal_f = __ballot(vf);
        if ((t & 63) == 0) {
            if (bal_b) atomicOr(flag, 1);
            if (bal_f) atomicOr(flag, 2);
        }
    }
}

// ---------------- K2abc: fully fused per-node pipeline ----------------
__device__ __forceinline__ float lnsilu16(float x, float g, float b) {
    float s = x;
#pragma unroll
    for (int m = 1; m < 16; m <<= 1) s += __shfl_xor(s, m, 16);
    float mu = s * 0.0625f;
    float d = x - mu;
    float s2 = d * d;
#pragma unroll
    for (int m = 1; m < 16; m <<= 1) s2 += __shfl_xor(s2, m, 16);
    float y = d * rsqrtf(s2 * 0.0625f + 1e-5f) * g + b;
    return y * sigf(y);
}

__global__ __launch_bounds__(256, 2) void k2abc(
    const float* __restrict__ attn_weight, const void* __restrict__ mask,
    const int* __restrict__ mflag,
    const int* __restrict__ f_idx, const float* __restrict__ edge_vec,
    const int* __restrict__ atom_num, const unsigned short* __restrict__ clh,
    const float* __restrict__ q_ws, const unsigned short* __restrict__ keyh,
    const float* __restrict__ TA, const float* __restrict__ CA,
    const float* __restrict__ rm0_w1, const float* __restrict__ rm0_b1,
    const float* __restrict__ rm0_g1, const float* __restrict__ rm0_be1,
    const float* __restrict__ rm0_w2, const float* __restrict__ rm0_b2,
    const float* __restrict__ rm0_g2, const float* __restrict__ rm0_be2,
    const float* __restrict__ rm0_w3, const float* __restrict__ rm0_b3,
    const unsigned short* __restrict__ fcwh, const float* __restrict__ fcb,
    const float* __restrict__ an_g, const float* __restrict__ an_b,
    const float* __restrict__ alpha_dot,
    const float* __restrict__ rv_w1, const float* __restrict__ rv_b1,
    const float* __restrict__ rv_g1, const float* __restrict__ rv_be1,
    const float* __restrict__ rv_w2, const float* __restrict__ rv_b2,
    const float* __restrict__ rv_g2, const float* __restrict__ rv_be2,
    const float* __restrict__ rv_w3, const float* __restrict__ rv_b3,
    float* __restrict__ outpre)
{
    __shared__ float qn[288];
    __shared__ float Ts[32];
    __shared__ float shS[32][9];
    __shared__ __align__(16) unsigned char poolS[32 * 200 * 2];
    float (*awS)[32] = (float(*)[32])poolS;
    float (*caS)[32] = (float(*)[32])(poolS + 4096);
    unsigned short (*mwbS)[200] = (unsigned short(*)[200])poolS;
    __shared__ unsigned short KDSh[32][96];   // pre-dotted key (bf16)
    __shared__ float h2mS[32][17];
    __shared__ float h2vS[32][17];
    __shared__ float lgS[32][8];
    __shared__ float alS[256];
    __shared__ float mxS[8], invS[8];
    __shared__ int idxk[32], maskk[32];

    int n = blockIdx.x, t = threadIdx.x;
    int mode = mflag[0];

    for (int i = t; i < 288; i += 256) qn[i] = q_ws[(size_t)n * 288 + i];
    if (t < 32) {
        int an = atom_num[n];
        Ts[t] = TA[an * 32 + t];
        int e = n * KNBR + t;
        idxk[t] = f_idx[e];
        maskk[t] = edge_masked(mask, mode, e) ? 1 : 0;
        float vx = edge_vec[(size_t)e * 3 + 0];
        float vy = edge_vec[(size_t)e * 3 + 1];
        float vz = edge_vec[(size_t)e * 3 + 2];
        float inv = 1.0f / (sqrtf(vx * vx + vy * vy + vz * vz) + 1e-12f);
        float x = vx * inv, y = vy * inv, z = vz * inv;
        shS[t][0] = 0.28209479177387814f;
        shS[t][1] = 0.4886025119029199f * y;
        shS[t][2] = 0.4886025119029199f * z;
        shS[t][3] = 0.4886025119029199f * x;
        shS[t][4] = 1.0925484305920792f * x * y;
        shS[t][5] = 1.0925484305920792f * y * z;
        shS[t][6] = 0.31539156525252005f * (3.0f * z * z - 1.0f);
        shS[t][7] = 1.0925484305920792f * x * z;
        shS[t][8] = 0.5462742152960396f * (x * x - y * y);
    }
    __syncthreads();
    for (int e2 = t; e2 < 1024; e2 += 256) {
        int ek = e2 >> 5, i = e2 & 31;
        awS[ek][i] = maskk[ek] ? 0.0f : attn_weight[((size_t)(n * KNBR + ek)) * 32 + i];
        caS[ek][i] = CA[(size_t)idxk[ek] * 32 + i];
    }
    // stage pre-dotted key rows: KDSh[e][p*32+c] = bf16(<key_l, sh_l>)
    for (int i = t; i < 32 * 96; i += 256) {
        int e = i / 96, j = i - e * 96;
        int p = j >> 5, c = j & 31;
        const unsigned short* kr = keyh + (size_t)idxk[e] * 288;
        float v;
        if (p == 0)      v = bf2f(kr[c]) * shS[e][0];
        else if (p == 1) v = bf2f(kr[32 + c]) * shS[e][1] + bf2f(kr[64 + c]) * shS[e][2]
                           + bf2f(kr[96 + c]) * shS[e][3];
        else             v = bf2f(kr[128 + c]) * shS[e][4] + bf2f(kr[160 + c]) * shS[e][5]
                           + bf2f(kr[192 + c]) * shS[e][6] + bf2f(kr[224 + c]) * shS[e][7]
                           + bf2f(kr[256 + c]) * shS[e][8];
        KDSh[e][j] = f2bf(v);
    }
    __syncthreads();

    // ===== phase A: edge MLPs (wave-parallel, 16-lane groups) =====
    {
        int g = t >> 4, j = t & 15;
        for (int ee = 0; ee < 2; ++ee) {
            int e = g + ee * 16;
            float accm = rm0_b1[j] + Ts[j] + caS[e][j];
            float accv = rv_b1[j] + Ts[16 + j] + caS[e][16 + j];
            const float* w1m = rm0_w1 + j * 416;
            const float* w1v = rv_w1 + j * 416;
#pragma unroll
            for (int i = 0; i < 32; i += 4) {
                float a0 = awS[e][i], a1 = awS[e][i + 1], a2 = awS[e][i + 2], a3 = awS[e][i + 3];
                accm = fmaf(a0, w1m[i], fmaf(a1, w1m[i+1], fmaf(a2, w1m[i+2], fmaf(a3, w1m[i+3], accm))));
                accv = fmaf(a0, w1v[i], fmaf(a1, w1v[i+1], fmaf(a2, w1v[i+2], fmaf(a3, w1v[i+3], accv))));
            }
            float hm = lnsilu16(accm, rm0_g1[j], rm0_be1[j]);
            float hv = lnsilu16(accv, rv_g1[j], rv_be1[j]);
            float am2 = rm0_b2[j], av2 = rv_b2[j];
#pragma unroll
            for (int i = 0; i < 16; ++i) {
                am2 = fmaf(__shfl(hm, i, 16), rm0_w2[j * 16 + i], am2);
                av2 = fmaf(__shfl(hv, i, 16), rv_w2[j * 16 + i], av2);
            }
            float h2m = lnsilu16(am2, rm0_g2[j], rm0_be2[j]);
            float h2v = lnsilu16(av2, rv_g2[j], rv_be2[j]);
            h2vS[e][j] = h2v;
            h2mS[e][j] = h2m;
        }
    }
    __syncthreads();   // awS/caS dead from here; pool becomes mwbS

    // ===== phase M: mwb[e][d] = bf16((rm0 layer3) * m0), uniform bb =====
#pragma unroll
    for (int bb = 0; bb < 6; ++bb) {
#pragma unroll
        for (int r2 = 0; r2 < 4; ++r2) {
            int oi = r2 * 256 + t;          // 0..1023
            int e = oi >> 5, c = oi & 31;
            int d = bb * 32 + c;
            const float4* w3 = (const float4*)(rm0_w3 + d * 16);
            float ew = rm0_b3[d];
#pragma unroll
            for (int i4 = 0; i4 < 4; ++i4) {
                float4 w = w3[i4];
                ew = fmaf(h2mS[e][i4 * 4 + 0], w.x, fmaf(h2mS[e][i4 * 4 + 1], w.y,
                     fmaf(h2mS[e][i4 * 4 + 2], w.z, fmaf(h2mS[e][i4 * 4 + 3], w.w, ew))));
            }
            float m0v;
            if (bb == 0)      m0v = qn[c] * shS[e][0];
            else if (bb == 1) m0v = qn[32 + c] * shS[e][1] + qn[64 + c] * shS[e][2]
                                  + qn[96 + c] * shS[e][3];
            else if (bb == 2) m0v = qn[128 + c] * shS[e][4] + qn[160 + c] * shS[e][5]
                                  + qn[192 + c] * shS[e][6] + qn[224 + c] * shS[e][7]
                                  + qn[256 + c] * shS[e][8];
            else              m0v = bf2f(KDSh[e][(bb - 3) * 32 + c]);
            mwbS[e][d] = f2bf(ew * m0v);
        }
    }
    __syncthreads();

    // ===== phase B: af = mwa @ fcw^T + fcb via MFMA; LN + smooth_leaky + logits ===
    {
        int wid = t >> 6, lane = t & 63;
        int lrow = lane & 15, kgrp = lane >> 4;
        f32x4 acc[4][2];
#pragma unroll
        for (int i = 0; i < 4; ++i)
#pragma unroll
            for (int m = 0; m < 2; ++m) acc[i][m] = (f32x4){0.f, 0.f, 0.f, 0.f};

#pragma unroll
        for (int ntl = 0; ntl < 4; ++ntl) {
            int col = wid * 64 + ntl * 16 + lrow;
            const bf16x8* brow = (const bf16x8*)(fcwh + (size_t)col * 192);
            bf16x8 bf[6];
#pragma unroll
            for (int kk = 0; kk < 6; ++kk) bf[kk] = brow[kk * 4 + kgrp];
#pragma unroll
            for (int kk = 0; kk < 6; ++kk) {
#pragma unroll
                for (int m = 0; m < 2; ++m) {
                    bf16x8 a8 = *(const bf16x8*)&mwbS[m * 16 + lrow][kk * 32 + kgrp * 8];
                    acc[ntl][m] = __builtin_amdgcn_mfma_f32_16x16x32_bf16(a8, bf[kk], acc[ntl][m], 0, 0, 0);
                }
            }
        }
#pragma unroll
        for (int ntl = 0; ntl < 4; ++ntl) {
            float fb = fcb[wid * 64 + ntl * 16 + lrow];
#pragma unroll
            for (int m = 0; m < 2; ++m)
#pragma unroll
                for (int r = 0; r < 4; ++r) acc[ntl][m][r] += fb;
        }
        float ang0 = an_g[lrow], ang1 = an_g[16 + lrow];
        float anb0 = an_b[lrow], anb1 = an_b[16 + lrow];
#pragma unroll
        for (int hh = 0; hh < 2; ++hh) {
            int h = wid * 2 + hh;
            float ad0 = alpha_dot[h * 32 + lrow], ad1 = alpha_dot[h * 32 + 16 + lrow];
#pragma unroll
            for (int m = 0; m < 2; ++m) {
#pragma unroll
                for (int r = 0; r < 4; ++r) {
                    float a = acc[2 * hh][m][r], b = acc[2 * hh + 1][m][r];
                    float su = a + b;
#pragma unroll
                    for (int mm = 1; mm < 16; mm <<= 1) su += __shfl_xor(su, mm, 16);
                    float mu = su * (1.0f / 32.0f);
                    float da = a - mu, db = b - mu;
                    float v2 = da * da + db * db;
#pragma unroll
                    for (int mm = 1; mm < 16; mm <<= 1) v2 += __shfl_xor(v2, mm, 16);
                    float rs = rsqrtf(v2 * (1.0f / 32.0f) + 1e-5f);
                    float y0 = da * rs * ang0 + anb0;
                    float y1 = db * rs * ang1 + anb1;
                    float sl0 = 0.6f * y0 + 0.4f * y0 * (2.0f * sigf(y0) - 1.0f);
                    float sl1 = 0.6f * y1 + 0.4f * y1 * (2.0f * sigf(y1) - 1.0f);
                    float lg = sl0 * ad0 + sl1 * ad1;
#pragma unroll
                    for (int mm = 1; mm < 16; mm <<= 1) lg += __shfl_xor(lg, mm, 16);
                    if (lrow == 0) {
                        int e = m * 16 + kgrp * 4 + r;
                        lgS[e][h] = maskk[e] ? -1e9f : lg;
                    }
                }
            }
        }
    }
    __syncthreads();

    // ===== softmax over k -> alS[k*8+h] =====
    if (t < 8) {
        float mx = -1e30f;
#pragma unroll
        for (int k = 0; k < 32; ++k) mx = fmaxf(mx, lgS[k][t]);
        float sum = 0.0f;
#pragma unroll
        for (int k = 0; k < 32; ++k) sum += __expf(lgS[k][t] - mx);
        mxS[t] = mx;
        invS[t] = 1.0f / sum;
    }
    __syncthreads();
    {
        int k = t >> 3, h = t & 7;
        alS[t] = __expf(lgS[k][h] - mxS[h]) * invS[h];
    }
    __syncthreads();

    // ===== phase C: vw recompute + alpha-weighted cluster aggregation ============
    {
        int c = t, h = c >> 5;
        float w3r[16];
        const float4* w3p = (const float4*)(rv_w3 + c * 16);
#pragma unroll
        for (int i4 = 0; i4 < 4; ++i4) {
            float4 w = w3p[i4];
            w3r[i4 * 4 + 0] = w.x; w3r[i4 * 4 + 1] = w.y;
            w3r[i4 * 4 + 2] = w.z; w3r[i4 * 4 + 3] = w.w;
        }
        float b3c = rv_b3[c];
        float acc[9];
#pragma unroll
        for (int m = 0; m < 9; ++m) acc[m] = 0.0f;
        for (int k = 0; k < 32; ++k) {
            float vw = b3c;
#pragma unroll
            for (int i = 0; i < 16; ++i) vw = fmaf(h2vS[k][i], w3r[i], vw);
            float av = alS[k * 8 + h] * vw;
            const unsigned short* crow = clh + (size_t)idxk[k] * 2304 + c;
#pragma unroll
            for (int m = 0; m < 9; ++m) acc[m] = fmaf(av, bf2f(crow[m * 256]), acc[m]);
        }
#pragma unroll
        for (int m = 0; m < 9; ++m) outpre[((size_t)n * 9 + m) * 256 + c] = acc[m];
    }
}

// ---------------- K5: final so3_linear via MFMA (wzh bf16), in-place on d_out ----
__global__ __launch_bounds__(256) void k5_final(
    const unsigned short* __restrict__ wzh, const float* __restrict__ bz,
    float* __restrict__ io)
{
    __shared__ __align__(16) unsigned short Xb[32][264];
    __shared__ int rr[32];
    int b = blockIdx.x, t = threadIdx.x;
    int l, vr0, nm, moff;
    if (b < 64)       { l = 0; vr0 = b * 32;         nm = 1; moff = 0; }
    else if (b < 256) { l = 1; vr0 = (b - 64) * 32;  nm = 3; moff = 1; }
    else              { l = 2; vr0 = (b - 256) * 32; nm = 5; moff = 4; }
    if (t < 32) {
        int vr = vr0 + t;
        int n = vr / nm, m = moff + vr % nm;
        rr[t] = n * 9 + m;
    }
    __syncthreads();
    for (int e = t; e < 32 * 256; e += 256) {
        int r = e >> 8, c = e & 255;
        Xb[r][c] = f2bf(io[(size_t)rr[r] * 256 + c]);
    }
    __syncthreads();

    int wid = t >> 6, lane = t & 63;
    int lrow = lane & 15, kgrp = lane >> 4;
    f32x4 acc[2][4];
#pragma unroll
    for (int mt = 0; mt < 2; ++mt)
#pragma unroll
        for (int ntl = 0; ntl < 4; ++ntl) acc[mt][ntl] = (f32x4){0.f, 0.f, 0.f, 0.f};

#pragma unroll
    for (int ntl = 0; ntl < 4; ++ntl) {
        int dcol = wid * 64 + ntl * 16 + lrow;
        const bf16x8* brow = (const bf16x8*)(wzh + ((size_t)l * 256 + dcol) * 256);
#pragma unroll
        for (int kk = 0; kk < 8; ++kk) {
            bf16x8 b8 = brow[kk * 4 + kgrp];
#pragma unroll
            for (int mt = 0; mt < 2; ++mt) {
                bf16x8 a8 = *(const bf16x8*)&Xb[mt * 16 + lrow][kk * 32 + kgrp * 8];
                acc[mt][ntl] = __builtin_amdgcn_mfma_f32_16x16x32_bf16(a8, b8, acc[mt][ntl], 0, 0, 0);
            }
        }
    }
#pragma unroll
    for (int ntl = 0; ntl < 4; ++ntl) {
        int dcol = wid * 64 + ntl * 16 + lrow;
        float bias = (l == 0) ? bz[dcol] : 0.0f;
#pragma unroll
        for (int mt = 0; mt < 2; ++mt) {
#pragma unroll
            for (int r = 0; r < 4; ++r) {
                int row = mt * 16 + kgrp * 4 + r;
                io[(size_t)rr[row] * 256 + dcol] = acc[mt][ntl][r] + bias;
            }
        }
    }
}

// ---------------- launch ----------------
extern "C" void kernel_launch(void* const* d_in, const int* in_sizes, int n_in,
                              void* d_out, int out_size, void* d_ws, size_t ws_size,
                              hipStream_t stream)
{
    (void)in_sizes; (void)n_in; (void)out_size; (void)ws_size;

    const float* node_irreps = (const float*)d_in[1];
    const float* edge_vec    = (const float*)d_in[3];
    const float* attn_weight = (const float*)d_in[4];
    const int*   atom_num    = (const int*)d_in[5];
    const void*  attn_mask   = d_in[6];
    const int*   f_idx       = (const int*)d_in[7];
    const float* clus        = (const float*)d_in[8];
    const float* tgt_emb     = (const float*)d_in[9];
    const float* W_dot       = (const float*)d_in[10];
    const float* b_dot       = (const float*)d_in[11];
    const float* rm0_w1 = (const float*)d_in[12];
    const float* rm0_b1 = (const float*)d_in[13];
    const float* rm0_g1 = (const float*)d_in[14];
    const float* rm0_be1 = (const float*)d_in[15];
    const float* rm0_w2 = (const float*)d_in[16];
    const float* rm0_b2 = (const float*)d_in[17];
    const float* rm0_g2 = (const float*)d_in[18];
    const float* rm0_be2 = (const float*)d_in[19];
    const float* rm0_w3 = (const float*)d_in[20];
    const float* rm0_b3 = (const float*)d_in[21];
    const float* fcw = (const float*)d_in[22];
    const float* fcb = (const float*)d_in[23];
    const float* an_g = (const float*)d_in[24];
    const float* an_b = (const float*)d_in[25];
    const float* alpha_dot = (const float*)d_in[26];
    const float* rv_w1 = (const float*)d_in[27];
    const float* rv_b1 = (const float*)d_in[28];
    const float* rv_g1 = (const float*)d_in[29];
    const float* rv_be1 = (const float*)d_in[30];
    const float* rv_w2 = (const float*)d_in[31];
    const float* rv_b2 = (const float*)d_in[32];
    const float* rv_g2 = (const float*)d_in[33];
    const float* rv_be2 = (const float*)d_in[34];
    const float* rv_w3 = (const float*)d_in[35];
    const float* rv_b3 = (const float*)d_in[36];
    const float* wz = (const float*)d_in[37];
    const float* bz = (const float*)d_in[38];

    float* ws = (float*)d_ws;
    int* flag = (int*)d_ws;
    float* q_ws = ws + 16;                                                   // 2048*288 f32
    unsigned short* keyh = (unsigned short*)(q_ws + (size_t)NNODE * 288);    // 2048*288 bf16
    float* TA_ws = (float*)(keyh + (size_t)MCLUS * 288);                     // 256*32
    float* CA_ws = TA_ws + 256 * 32;                                         // 2048*32
    unsigned short* clh = (unsigned short*)(CA_ws + (size_t)MCLUS * 32);     // 2048*2304 bf16
    unsigned short* fcwh = (unsigned short*)(clh + (size_t)MCLUS * 2304);    // 256*192 bf16
    unsigned short* wzh = fcwh + 256 * 192;                                  // 3*256*256 bf16
    float* outpre = (float*)d_out;

    hipMemsetAsync(flag, 0, sizeof(int), stream);
    kprep<<<4512, 256, 0, stream>>>(
        (const unsigned int*)attn_mask, flag,
        clus, fcw, wz, clh, fcwh, wzh,
        tgt_emb, rm0_w1, rv_w1, TA_ws, CA_ws,
        node_irreps, W_dot, b_dot, q_ws, keyh);
    k2abc<<<NNODE, 256, 0, stream>>>(
        attn_weight, attn_mask, flag, f_idx, edge_vec, atom_num, clh,
        q_ws, keyh, TA_ws, CA_ws,
        rm0_w1, rm0_b1, rm0_g1, rm0_be1, rm0_w2, rm0_b2, rm0_g2, rm0_be2, rm0_w3, rm0_b3,
        fcwh, fcb, an_g, an_b, alpha_dot,
        rv_w1, rv_b1, rv_g1, rv_be1, rv_w2, rv_b2, rv_g2, rv_be2, rv_w3, rv_b3,
        outpre);
    k5_final<<<576, 256, 0, stream>>>(wzh, bz, outpre);
}